// Round 1
// baseline (16414.998 us; speedup 1.0000x reference)
//
#include <hip/hip_runtime.h>
#include <hip/hip_bf16.h>

typedef __bf16 bf16_t;
typedef __bf16 bf16x8 __attribute__((ext_vector_type(8)));
typedef float  f32x4  __attribute__((ext_vector_type(4)));
typedef float  f32x2  __attribute__((ext_vector_type(2)));

#define Bx 128
#define Sx 128
#define Tx 128
#define Ex 256
#define Hx 512
#define H2 1024
#define G3 1536
#define KX 1280   // E + 2H  (GRU input width)
#define KP 1792   // E + H + 2H (preout width)

#define NBLK 256  // persistent grid: 256 blocks x 256 threads (co-resident, 1/CU)

// ---- output section offsets (elements, fp32) ----
#define OUT_STATES 0
#define OUT_HID    8388608   // B*T*H
#define OUT_PRE    8454144   // + B*H
#define OUT_CELL   16842752  // + B*T*H

__device__ __forceinline__ float fast_tanh(float x){
  float e = __expf(2.0f*x);
  return 1.0f - 2.0f/(e + 1.0f);   // safe at +/-inf
}
__device__ __forceinline__ float fast_sigmoid(float x){
  return 1.0f/(1.0f + __expf(-x));
}

// load 8 contiguous fp32 and round to bf16x8 (RNE via HW cvt)
__device__ __forceinline__ bf16x8 ld_cvt8(const float* p){
  f32x4 a = *(const f32x4*)p;
  f32x4 b = *(const f32x4*)(p+4);
  bf16x8 r;
  r[0]=(bf16_t)a[0]; r[1]=(bf16_t)a[1]; r[2]=(bf16_t)a[2]; r[3]=(bf16_t)a[3];
  r[4]=(bf16_t)b[0]; r[5]=(bf16_t)b[1]; r[6]=(bf16_t)b[2]; r[7]=(bf16_t)b[3];
  return r;
}

// NT GEMM tile (both operands already bf16): C[16,16] += A[16,K] * W[16,K]^T
// gfx950 layouts: A/B frag: row=lane&15, k=(lane>>4)*8+j ; D: row=(lane>>4)*4+r, col=lane&15
__device__ __forceinline__ f32x4 gemm_tile_bb(const bf16_t* A, int lda,
                                              const bf16_t* W, int ldw, int K, int lane){
  const int quad = lane >> 4, c = lane & 15;
  const bf16_t* pa = A + c*lda + quad*8;
  const bf16_t* pb = W + c*ldw + quad*8;
  f32x4 acc = {0.f,0.f,0.f,0.f};
  for (int k = 0; k < K; k += 32)
    acc = __builtin_amdgcn_mfma_f32_16x16x32_bf16(*(const bf16x8*)(pa+k),
                                                  *(const bf16x8*)(pb+k), acc, 0, 0, 0);
  return acc;
}

__device__ __forceinline__ void store_tile_f32(float* C, int ldc, f32x4 acc, int lane){
  const int quad = lane >> 4, c = lane & 15;
  #pragma unroll
  for (int r = 0; r < 4; r++) C[(quad*4 + r)*ldc + c] = acc[r];
}

// ---------------- device-scope grid barrier (persistent kernel) -----------------------
// barv[0] = arrival counter, barv[1] = generation. Agent-scope atomics: release emits
// L2 writeback, acquire emits L2/L1 invalidate -> cross-XCD visibility of plain stores.
__device__ __forceinline__ void gsync(unsigned* barv, unsigned next){
  __syncthreads();
  if (threadIdx.x == 0){
    unsigned prev = __hip_atomic_fetch_add(&barv[0], 1u, __ATOMIC_ACQ_REL,
                                           __HIP_MEMORY_SCOPE_AGENT);
    if (prev == (unsigned)(NBLK - 1)){
      __hip_atomic_store(&barv[0], 0u, __ATOMIC_RELAXED, __HIP_MEMORY_SCOPE_AGENT);
      __hip_atomic_store(&barv[1], next, __ATOMIC_RELEASE, __HIP_MEMORY_SCOPE_AGENT);
    } else {
      // relaxed spin (no per-iteration cache invalidate), one acquire fence on exit
      while (__hip_atomic_load(&barv[1], __ATOMIC_RELAXED,
                               __HIP_MEMORY_SCOPE_AGENT) != next)
        __builtin_amdgcn_s_sleep(2);
      __builtin_amdgcn_fence(__ATOMIC_ACQUIRE, "agent");
    }
  }
  __syncthreads();
}

__global__ void init_bar(unsigned* barv){ barv[0] = 0u; barv[1] = 0u; }

// ---------------- fp32 -> bf16 convert (n % 4 == 0) ------------------------------------
__global__ void cvt_kernel(const float* __restrict__ in, bf16_t* __restrict__ out, int n){
  const int i = (blockIdx.x*256 + threadIdx.x)*4;
  if (i < n){
    f32x4 v = *(const f32x4*)(in + i);
    bf16_t o[4]; o[0]=(bf16_t)v[0]; o[1]=(bf16_t)v[1]; o[2]=(bf16_t)v[2]; o[3]=(bf16_t)v[3];
    *(ulong1*)(out + i) = *(ulong1*)o;
  }
}

// ---------------- bridge: h0 = tanh(encoder_final @ W_bridge^T + b_bridge) -------------
__global__ void bridge_kernel(const float* __restrict__ ef, const float* __restrict__ Wb,
                              const float* __restrict__ bb,
                              float* __restrict__ hf, bf16_t* __restrict__ hb){
  const int b = blockIdx.x;        // 128
  const int h = threadIdx.x;       // 512
  __shared__ float efs[H2];
  for (int k = threadIdx.x; k < H2; k += blockDim.x) efs[k] = ef[b*H2 + k];
  __syncthreads();
  const float* wrow = Wb + h*H2;
  float acc = bb[h];
  for (int k = 0; k < H2; k += 4){
    f32x4 w = *(const f32x4*)(wrow + k);
    acc += efs[k]*w[0] + efs[k+1]*w[1] + efs[k+2]*w[2] + efs[k+3]*w[3];
  }
  float v = fast_tanh(acc);
  hf[b*Hx + h] = v;
  hb[b*Hx + h] = (bf16_t)v;
}

// ---------------- proj_key = encoder_hidden @ W_key^T  (16384x512, K=1024) -------------
__global__ void pk_gemm(const float* __restrict__ eh, const bf16_t* __restrict__ Wkb,
                        bf16_t* __restrict__ pk){
  const int gwid = (blockIdx.x*blockDim.x + threadIdx.x) >> 6;  // 0..32767
  const int lane = threadIdx.x & 63;
  const int quad = lane >> 4, c = lane & 15;
  const int mt = gwid >> 5;   // 1024 m-tiles
  const int nt = gwid & 31;   // 32 n-tiles
  const float*  pa = eh  + (mt*16 + c)*H2 + quad*8;
  const bf16_t* pb = Wkb + (nt*16 + c)*H2 + quad*8;
  f32x4 acc = {0.f,0.f,0.f,0.f};
  for (int k = 0; k < H2; k += 32)
    acc = __builtin_amdgcn_mfma_f32_16x16x32_bf16(ld_cvt8(pa + k),
                                                  *(const bf16x8*)(pb + k), acc, 0,0,0);
  bf16_t* C = pk + mt*16*Hx + nt*16;
  #pragma unroll
  for (int r = 0; r < 4; r++) C[(quad*4 + r)*Hx + c] = (bf16_t)acc[r];
}

// ---------------- persistent loop kernel: 128 steps, 3 grid barriers per step ----------
__global__ void __launch_bounds__(256)
loop_kernel(const float* __restrict__ trg, const float* __restrict__ eh,
            const float* __restrict__ ven, const bf16_t* __restrict__ pk,
            const bf16_t* __restrict__ Wqb, const bf16_t* __restrict__ Whhb,
            const bf16_t* __restrict__ Wihb, const float* __restrict__ bih,
            const float* __restrict__ bhh, const bf16_t* __restrict__ Wpb,
            bf16_t* __restrict__ xbuf, float* __restrict__ qf, float* __restrict__ ghf,
            float* __restrict__ hf, bf16_t* __restrict__ hb,
            float* __restrict__ states, float* __restrict__ pre,
            unsigned* __restrict__ barv){
  const int tid  = threadIdx.x;
  const int lane = tid & 63;
  const int wid  = tid >> 6;
  const int blk  = blockIdx.x;          // 0..255
  const int gw   = blk*4 + wid;         // 0..1023
  const int quad = lane >> 4, c16 = lane & 15;

  // phase-B identity (one (b,half) job per block)
  const int b    = blk >> 1;
  const int half = blk & 1;
  const int d0   = half*Hx + tid*2;
  const float* ehb = eh + b*Sx*H2;

  __shared__ float sc[Sx];
  __shared__ float smax_s, ssum_s;

  // v_energy is step-invariant: load once
  float vv[8];
  #pragma unroll
  for (int i = 0; i < 8; i++) vv[i] = ven[i*64 + lane];

  unsigned gen = 0;

  for (int t = 0; t < Tx; t++){
    // ================= Phase A: q = h@Wq^T, gh = h@Whh^T =================
    if (gw < 256){
      const int mt = gw >> 5, nt = gw & 31;
      f32x4 acc = gemm_tile_bb(hb + mt*16*Hx, Hx, Wqb + nt*16*Hx, Hx, Hx, lane);
      store_tile_f32(qf + mt*16*Hx + nt*16, Hx, acc, lane);
    } else {
      const int idx = gw - 256;              // 0..767
      const int mt = idx/96, nt = idx%96;
      f32x4 acc = gemm_tile_bb(hb + mt*16*Hx, Hx, Whhb + nt*16*Hx, Hx, Hx, lane);
      store_tile_f32(ghf + mt*16*G3 + nt*16, G3, acc, lane);
    }
    gsync(barv, ++gen);

    // ================= Phase B: scores -> softmax -> context =================
    {
      float qv[8];
      #pragma unroll
      for (int i = 0; i < 8; i++) qv[i] = qf[b*Hx + i*64 + lane];

      for (int j = 0; j < 32; j++){
        const int s = wid*32 + j;
        const bf16_t* row = pk + (b*Sx + s)*Hx;
        float p = 0.f;
        #pragma unroll
        for (int i = 0; i < 8; i++)
          p += fast_tanh(qv[i] + (float)row[i*64 + lane])*vv[i];
        #pragma unroll
        for (int o = 32; o; o >>= 1) p += __shfl_xor(p, o, 64);
        if (lane == 0) sc[s] = p;
      }
      __syncthreads();
      if (tid < 64){
        float m = fmaxf(sc[tid], sc[tid+64]);
        #pragma unroll
        for (int o = 32; o; o >>= 1) m = fmaxf(m, __shfl_xor(m, o, 64));
        if (tid == 0) smax_s = m;
      }
      __syncthreads();
      if (tid < 128) sc[tid] = __expf(sc[tid] - smax_s);
      __syncthreads();
      if (tid < 64){
        float ssum = sc[tid] + sc[tid+64];
        #pragma unroll
        for (int o = 32; o; o >>= 1) ssum += __shfl_xor(ssum, o, 64);
        if (tid == 0) ssum_s = ssum;
      }
      __syncthreads();
      const float inv = 1.0f/ssum_s;
      float c0 = 0.f, c1 = 0.f;
      #pragma unroll 4
      for (int s = 0; s < Sx; s++){
        const float a = sc[s];
        f32x2 v = *(const f32x2*)(ehb + s*H2 + d0);
        c0 += a*v[0];
        c1 += a*v[1];
      }
      c0 *= inv; c1 *= inv;
      bf16_t cb[2]; cb[0] = (bf16_t)c0; cb[1] = (bf16_t)c1;
      *(uint1*)(xbuf + b*KX + Ex + d0) = *(uint1*)cb;
      if (half == 0) xbuf[b*KX + tid] = (bf16_t)trg[(b*Tx + t)*Ex + tid];
    }
    gsync(barv, ++gen);

    // ================= Phase C: gi GEMM + GRU combine; preout-ctx partial ============
    if (gw < 256){
      const int mt = gw >> 5, ntp = gw & 31;
      const bf16_t* A  = xbuf + (mt*16 + c16)*KX + quad*8;
      const bf16_t* B0 = Wihb + (ntp*16 + c16)*KX + quad*8;
      const bf16_t* B1 = B0 + Hx*KX;
      const bf16_t* B2 = B0 + H2*KX;
      f32x4 ar = {0.f,0.f,0.f,0.f}, az = ar, an = ar;
      for (int k = 0; k < KX; k += 32){
        bf16x8 a = *(const bf16x8*)(A + k);
        ar = __builtin_amdgcn_mfma_f32_16x16x32_bf16(a, *(const bf16x8*)(B0+k), ar, 0,0,0);
        az = __builtin_amdgcn_mfma_f32_16x16x32_bf16(a, *(const bf16x8*)(B1+k), az, 0,0,0);
        an = __builtin_amdgcn_mfma_f32_16x16x32_bf16(a, *(const bf16x8*)(B2+k), an, 0,0,0);
      }
      const int j = ntp*16 + c16;
      const float bir = bih[j], biz = bih[Hx+j], bin = bih[H2+j];
      const float bhr = bhh[j], bhz = bhh[Hx+j], bhn = bhh[H2+j];
      #pragma unroll
      for (int r = 0; r < 4; r++){
        const int b_ = mt*16 + quad*4 + r;
        const float hr = ghf[b_*G3 + j]       + bhr;
        const float hz = ghf[b_*G3 + Hx + j]  + bhz;
        const float hn = ghf[b_*G3 + H2 + j]  + bhn;
        const float rg = fast_sigmoid(ar[r] + bir + hr);
        const float zg = fast_sigmoid(az[r] + biz + hz);
        const float ng = fast_tanh(an[r] + bin + rg*hn);
        const float hold = hf[b_*Hx + j];
        const float hnew = (1.0f - zg)*ng + zg*hold;
        hf[b_*Hx + j] = hnew;
        hb[b_*Hx + j] = (bf16_t)hnew;
        states[(b_*Tx + t)*Hx + j] = hnew;
      }
    } else if (gw < 512){
      // pre_ctx = ctx @ Wp[:,768:1792]^T  -> pre (ctx partial, fp32)
      const int idx = gw - 256;
      const int mt2 = idx >> 5, nt2 = idx & 31;
      const bf16_t* A = xbuf + (mt2*16 + c16)*KX + Ex + quad*8;
      const bf16_t* B = Wpb + (nt2*16 + c16)*KP + (Ex + Hx) + quad*8;
      f32x4 acc = {0.f,0.f,0.f,0.f};
      for (int k = 0; k < H2; k += 32)
        acc = __builtin_amdgcn_mfma_f32_16x16x32_bf16(*(const bf16x8*)(A+k),
                                                      *(const bf16x8*)(B+k), acc, 0,0,0);
      #pragma unroll
      for (int r = 0; r < 4; r++){
        const int b_ = mt2*16 + quad*4 + r;
        pre[(b_*Tx + t)*Hx + nt2*16 + c16] = acc[r];
      }
    }
    gsync(barv, ++gen);
  }
}

// ------- preout += [trg | states] @ Wp[:,0:768]^T  (adds onto ctx partial in pre) -----
__global__ void preout_gemm(const bf16_t* __restrict__ trgb, const float* __restrict__ states,
                            const bf16_t* __restrict__ Wpb, float* __restrict__ pre){
  const int gwid = (blockIdx.x*blockDim.x + threadIdx.x) >> 6;  // 0..32767
  const int lane = threadIdx.x & 63;
  const int quad = lane >> 4, c16 = lane & 15;
  const int mt = gwid >> 5, nt = gwid & 31;
  const int m = mt*16 + c16;
  const bf16_t* Bp = Wpb + (nt*16 + c16)*KP + quad*8;
  f32x4 acc = {0.f,0.f,0.f,0.f};
  const bf16_t* Ae = trgb + m*Ex + quad*8;
  for (int k = 0; k < Ex; k += 32)
    acc = __builtin_amdgcn_mfma_f32_16x16x32_bf16(*(const bf16x8*)(Ae+k),
                                                  *(const bf16x8*)(Bp+k), acc, 0,0,0);
  const float* As = states + m*Hx + quad*8;
  for (int k = 0; k < Hx; k += 32)
    acc = __builtin_amdgcn_mfma_f32_16x16x32_bf16(ld_cvt8(As+k),
                                                  *(const bf16x8*)(Bp+Ex+k), acc, 0,0,0);
  float* C = pre + mt*16*Hx + nt*16;
  #pragma unroll
  for (int r = 0; r < 4; r++){
    const int o = (quad*4 + r)*Hx + c16;
    C[o] = acc[r] + C[o];
  }
}

// ---------------- hidden (hT) + cell_state (zeros) ------------------------------------
__global__ void finalize_kernel(const float* __restrict__ hf,
                                float* __restrict__ hid, float* __restrict__ cell){
  const int i = blockIdx.x*256 + threadIdx.x;  // 0..65535
  hid[i]  = hf[i];
  cell[i] = 0.0f;   // also wipes the grid-barrier scratch living at cell[0..1]
}

extern "C" void kernel_launch(void* const* d_in, const int* in_sizes, int n_in,
                              void* d_out, int out_size, void* d_ws, size_t ws_size,
                              hipStream_t stream){
  // --- input remap: find W_ih by its unique size (1536*1280); masks may be absent ---
  int shift = 0;
  for (int i = 0; i < n_in; i++){
    if (in_sizes[i] == 1966080){ shift = i - 8; break; }
  }
  #define IN(k) (((k) < 3) ? d_in[(k)] : d_in[(k) + shift])
  const float* trg = (const float*)IN(0);
  const float* eh  = (const float*)IN(1);
  const float* ef  = (const float*)IN(2);
  const float* Wk  = (const float*)IN(5);
  const float* Wq  = (const float*)IN(6);
  const float* ven = (const float*)IN(7);
  const float* Wih = (const float*)IN(8);
  const float* Whh = (const float*)IN(9);
  const float* bih = (const float*)IN(10);
  const float* bhh = (const float*)IN(11);
  const float* Wb  = (const float*)IN(12);
  const float* bb  = (const float*)IN(13);
  const float* Wp  = (const float*)IN(14);
  #undef IN

  // --- ws layout (bytes), total 35,848,192 (~34.2 MB) ---
  char* ws = (char*)d_ws;
  bf16_t* xbuf = (bf16_t*)(ws + 0);          //   327,680
  float*  hf   = (float* )(ws + 327680);     //   262,144
  bf16_t* hb   = (bf16_t*)(ws + 589824);     //   131,072
  float*  qf   = (float* )(ws + 720896);     //   262,144
  float*  ghf  = (float* )(ws + 983040);     //   786,432
  bf16_t* Wkb  = (bf16_t*)(ws + 1769472);    // 1,048,576
  bf16_t* Wqb  = (bf16_t*)(ws + 2818048);    //   524,288
  bf16_t* Whhb = (bf16_t*)(ws + 3342336);    // 1,572,864
  bf16_t* Wihb = (bf16_t*)(ws + 4915200);    // 3,932,160
  bf16_t* Wpb  = (bf16_t*)(ws + 8847360);    // 1,835,008
  bf16_t* trgb = (bf16_t*)(ws + 10682368);   // 8,388,608
  bf16_t* pk   = (bf16_t*)(ws + 19070976);   // 16,777,216

  float* out    = (float*)d_out;
  float* states = out + OUT_STATES;
  float* hid    = out + OUT_HID;
  float* pre    = out + OUT_PRE;
  float* cell   = out + OUT_CELL;

  // grid-barrier scratch lives in the cell output region (finalize zeroes it later)
  unsigned* barv = (unsigned*)cell;

  // one-shot converts (fp32 -> bf16)
  cvt_kernel<<<dim3(512),  dim3(256), 0, stream>>>(Wk,  Wkb,  524288);
  cvt_kernel<<<dim3(256),  dim3(256), 0, stream>>>(Wq,  Wqb,  262144);
  cvt_kernel<<<dim3(768),  dim3(256), 0, stream>>>(Whh, Whhb, 786432);
  cvt_kernel<<<dim3(1920), dim3(256), 0, stream>>>(Wih, Wihb, 1966080);
  cvt_kernel<<<dim3(896),  dim3(256), 0, stream>>>(Wp,  Wpb,  917504);
  cvt_kernel<<<dim3(4096), dim3(256), 0, stream>>>(trg, trgb, 4194304);

  bridge_kernel<<<dim3(Bx), dim3(Hx), 0, stream>>>(ef, Wb, bb, hf, hb);
  pk_gemm<<<dim3(8192), dim3(256), 0, stream>>>(eh, Wkb, pk);
  init_bar<<<dim3(1), dim3(1), 0, stream>>>(barv);

  // one persistent kernel replaces 384 per-step launches
  loop_kernel<<<dim3(NBLK), dim3(256), 0, stream>>>(trg, eh, ven, pk,
                                                    Wqb, Whhb, Wihb, bih, bhh, Wpb,
                                                    xbuf, qf, ghf, hf, hb,
                                                    states, pre, barv);

  preout_gemm<<<dim3(8192), dim3(256), 0, stream>>>(trgb, states, Wpb, pre);
  finalize_kernel<<<dim3(256), dim3(256), 0, stream>>>(hf, hid, cell);
}

// Round 3
// 15559.308 us; speedup vs baseline: 1.0550x; 1.0550x over previous
//
#include <hip/hip_runtime.h>
#include <hip/hip_bf16.h>

typedef __bf16 bf16_t;
typedef __bf16 bf16x8 __attribute__((ext_vector_type(8)));
typedef __bf16 bf16x2 __attribute__((ext_vector_type(2)));
typedef float  f32x4  __attribute__((ext_vector_type(4)));
typedef float  f32x2  __attribute__((ext_vector_type(2)));

#define Bx 128
#define Sx 128
#define Tx 128
#define Ex 256
#define Hx 512
#define H2 1024
#define G3 1536
#define KX 1280   // E + 2H  (GRU input width)
#define KP 1792   // E + H + 2H (preout width)

#define NBLK 256  // persistent grid: 256 blocks x 256 threads (1 block/CU)
#define NGRP 16   // barrier groups (separate cache lines)

// ---- output section offsets (elements, fp32) ----
#define OUT_STATES 0
#define OUT_HID    8388608   // B*T*H
#define OUT_PRE    8454144   // + B*H
#define OUT_CELL   16842752  // + B*T*H

__device__ __forceinline__ float fast_tanh(float x){
  float e = __expf(2.0f*x);
  return 1.0f - 2.0f/(e + 1.0f);   // safe at +/-inf
}
__device__ __forceinline__ float fast_sigmoid(float x){
  return 1.0f/(1.0f + __expf(-x));
}

// load 8 contiguous fp32 and round to bf16x8 (RNE via HW cvt)
__device__ __forceinline__ bf16x8 ld_cvt8(const float* p){
  f32x4 a = *(const f32x4*)p;
  f32x4 b = *(const f32x4*)(p+4);
  bf16x8 r;
  r[0]=(bf16_t)a[0]; r[1]=(bf16_t)a[1]; r[2]=(bf16_t)a[2]; r[3]=(bf16_t)a[3];
  r[4]=(bf16_t)b[0]; r[5]=(bf16_t)b[1]; r[6]=(bf16_t)b[2]; r[7]=(bf16_t)b[3];
  return r;
}

// NT GEMM tile (both operands already bf16): C[16,16] += A[16,K] * W[16,K]^T
__device__ __forceinline__ f32x4 gemm_tile_bb(const bf16_t* A, int lda,
                                              const bf16_t* W, int ldw, int K, int lane){
  const int quad = lane >> 4, c = lane & 15;
  const bf16_t* pa = A + c*lda + quad*8;
  const bf16_t* pb = W + c*ldw + quad*8;
  f32x4 acc = {0.f,0.f,0.f,0.f};
  for (int k = 0; k < K; k += 32)
    acc = __builtin_amdgcn_mfma_f32_16x16x32_bf16(*(const bf16x8*)(pa+k),
                                                  *(const bf16x8*)(pb+k), acc, 0, 0, 0);
  return acc;
}

__device__ __forceinline__ void store_tile_f32(float* C, int ldc, f32x4 acc, int lane){
  const int quad = lane >> 4, c = lane & 15;
  #pragma unroll
  for (int r = 0; r < 4; r++) C[(quad*4 + r)*ldc + c] = acc[r];
}

// ---------------- hierarchical grid barrier ------------------------------------------
// barv layout (uint words): group counter g at barv[g*32] (128B apart, monotonic),
// generation word at barv[NGRP*32]. No resets: target = gen * (NBLK/NGRP).
__device__ __forceinline__ void gsync(unsigned* __restrict__ barv, unsigned next,
                                      int tid, int blk){
  __syncthreads();
  if (tid == 0){
    __builtin_amdgcn_fence(__ATOMIC_RELEASE, "agent");       // publish my writes (wbl2)
    __hip_atomic_fetch_add(&barv[(blk & (NGRP-1))*32], 1u,
                           __ATOMIC_RELAXED, __HIP_MEMORY_SCOPE_AGENT);
  }
  if (blk == 0){
    if (tid < NGRP){
      const unsigned target = next * (NBLK / NGRP);
      while (__hip_atomic_load(&barv[tid*32], __ATOMIC_RELAXED,
                               __HIP_MEMORY_SCOPE_AGENT) < target)
        __builtin_amdgcn_s_sleep(1);
    }
    __syncthreads();                                          // join pollers
    if (tid == 0){
      __builtin_amdgcn_fence(__ATOMIC_ACQUIRE, "agent");      // order polls < release
      __hip_atomic_store(&barv[NGRP*32], next, __ATOMIC_RELAXED,
                         __HIP_MEMORY_SCOPE_AGENT);
    }
  } else {
    if (tid == 0){
      while (__hip_atomic_load(&barv[NGRP*32], __ATOMIC_RELAXED,
                               __HIP_MEMORY_SCOPE_AGENT) < next)
        __builtin_amdgcn_s_sleep(8);
      __builtin_amdgcn_fence(__ATOMIC_ACQUIRE, "agent");      // invalidate stale L1/L2
    }
  }
  __syncthreads();
}

// FIXED: cover all NGRP*32+1 = 513 words (round-2 bug: only 256 threads launched,
// leaving group counters 8..15 and the generation word with garbage -> barrier collapse)
__global__ void init_bar(unsigned* barv){
  const int i = blockIdx.x*256 + threadIdx.x;
  if (i <= NGRP*32)
    __hip_atomic_store(&barv[i], 0u, __ATOMIC_RELAXED, __HIP_MEMORY_SCOPE_AGENT);
}

// ---------------- fp32 -> bf16 convert (n % 4 == 0) -----------------------------------
__global__ void cvt_kernel(const float* __restrict__ in, bf16_t* __restrict__ out, int n){
  const int i = (blockIdx.x*256 + threadIdx.x)*4;
  if (i < n){
    f32x4 v = *(const f32x4*)(in + i);
    bf16_t o[4]; o[0]=(bf16_t)v[0]; o[1]=(bf16_t)v[1]; o[2]=(bf16_t)v[2]; o[3]=(bf16_t)v[3];
    *(ulong1*)(out + i) = *(ulong1*)o;
  }
}

// ---------------- bridge: h0 = tanh(encoder_final @ W_bridge^T + b_bridge) -------------
__global__ void bridge_kernel(const float* __restrict__ ef, const float* __restrict__ Wb,
                              const float* __restrict__ bb,
                              float* __restrict__ hf, bf16_t* __restrict__ hb){
  const int b = blockIdx.x;        // 128
  const int h = threadIdx.x;       // 512
  __shared__ float efs[H2];
  for (int k = threadIdx.x; k < H2; k += blockDim.x) efs[k] = ef[b*H2 + k];
  __syncthreads();
  const float* wrow = Wb + h*H2;
  float acc = bb[h];
  for (int k = 0; k < H2; k += 4){
    f32x4 w = *(const f32x4*)(wrow + k);
    acc += efs[k]*w[0] + efs[k+1]*w[1] + efs[k+2]*w[2] + efs[k+3]*w[3];
  }
  float v = fast_tanh(acc);
  hf[b*Hx + h] = v;
  hb[b*Hx + h] = (bf16_t)v;
}

// ---------------- proj_key = encoder_hidden @ W_key^T  (16384x512, K=1024) -------------
__global__ void pk_gemm(const float* __restrict__ eh, const bf16_t* __restrict__ Wkb,
                        bf16_t* __restrict__ pk){
  const int gwid = (blockIdx.x*blockDim.x + threadIdx.x) >> 6;  // 0..32767
  const int lane = threadIdx.x & 63;
  const int quad = lane >> 4, c = lane & 15;
  const int mt = gwid >> 5;   // 1024 m-tiles
  const int nt = gwid & 31;   // 32 n-tiles
  const float*  pa = eh  + (mt*16 + c)*H2 + quad*8;
  const bf16_t* pb = Wkb + (nt*16 + c)*H2 + quad*8;
  f32x4 acc = {0.f,0.f,0.f,0.f};
  for (int k = 0; k < H2; k += 32)
    acc = __builtin_amdgcn_mfma_f32_16x16x32_bf16(ld_cvt8(pa + k),
                                                  *(const bf16x8*)(pb + k), acc, 0,0,0);
  bf16_t* C = pk + mt*16*Hx + nt*16;
  #pragma unroll
  for (int r = 0; r < 4; r++) C[(quad*4 + r)*Hx + c] = (bf16_t)acc[r];
}

// ---------------- persistent loop kernel: 128 steps, 3 grid barriers per step ----------
__global__ void __launch_bounds__(256)
loop_kernel(const float* __restrict__ trg, const float* __restrict__ eh,
            const bf16_t* __restrict__ ehb,            // bf16 copy of eh (may be null)
            const float* __restrict__ ven, const bf16_t* __restrict__ pk,
            const bf16_t* __restrict__ Wqb, const bf16_t* __restrict__ Whhb,
            const bf16_t* __restrict__ Wihb, const float* __restrict__ bih,
            const float* __restrict__ bhh, const bf16_t* __restrict__ Wpb,
            bf16_t* __restrict__ xbuf, float* __restrict__ qf, float* __restrict__ ghf,
            float* __restrict__ hf, bf16_t* __restrict__ hb,
            float* __restrict__ states, float* __restrict__ pre,
            unsigned* __restrict__ barv){
  const int tid  = threadIdx.x;
  const int lane = tid & 63;
  const int wid  = tid >> 6;
  const int blk  = blockIdx.x;          // 0..255
  const int gw   = blk*4 + wid;         // 0..1023
  const int quad = lane >> 4, c16 = lane & 15;

  // phase-B identity (one (b,half) job per block)
  const int b    = blk >> 1;
  const int half = blk & 1;
  const int d0   = half*Hx + tid*2;

  __shared__ float sc[Sx];
  __shared__ float smax_s, ssum_s;

  // v_energy is step-invariant: lane owns h = lane*8 .. lane*8+7
  float vv[8];
  *(f32x4*)(vv)   = *(const f32x4*)(ven + lane*8);
  *(f32x4*)(vv+4) = *(const f32x4*)(ven + lane*8 + 4);

  unsigned gen = 0;

  for (int t = 0; t < Tx; t++){
    // ================= Phase A: q = h@Wq^T, gh = h@Whh^T =================
    if (gw < 256){
      const int mt = gw >> 5, nt = gw & 31;
      f32x4 acc = gemm_tile_bb(hb + mt*16*Hx, Hx, Wqb + nt*16*Hx, Hx, Hx, lane);
      store_tile_f32(qf + mt*16*Hx + nt*16, Hx, acc, lane);
    } else {
      const int idx = gw - 256;              // 0..767
      const int mt = idx/96, nt = idx%96;
      f32x4 acc = gemm_tile_bb(hb + mt*16*Hx, Hx, Whhb + nt*16*Hx, Hx, Hx, lane);
      store_tile_f32(ghf + mt*16*G3 + nt*16, G3, acc, lane);
    }
    gsync(barv, ++gen, tid, blk);

    // ================= Phase B: scores -> softmax -> context =================
    {
      float qv[8];
      *(f32x4*)(qv)   = *(const f32x4*)(qf + b*Hx + lane*8);
      *(f32x4*)(qv+4) = *(const f32x4*)(qf + b*Hx + lane*8 + 4);

      #pragma unroll 2
      for (int j = 0; j < 32; j++){
        const int s = wid*32 + j;
        bf16x8 rw = *(const bf16x8*)(pk + (size_t)(b*Sx + s)*Hx + lane*8);
        float p = 0.f;
        #pragma unroll
        for (int i = 0; i < 8; i++)
          p += fast_tanh(qv[i] + (float)rw[i])*vv[i];
        #pragma unroll
        for (int o = 32; o; o >>= 1) p += __shfl_xor(p, o, 64);
        if (lane == 0) sc[s] = p;
      }
      __syncthreads();
      if (tid < 64){
        float m = fmaxf(sc[tid], sc[tid+64]);
        #pragma unroll
        for (int o = 32; o; o >>= 1) m = fmaxf(m, __shfl_xor(m, o, 64));
        if (tid == 0) smax_s = m;
      }
      __syncthreads();
      if (tid < 128) sc[tid] = __expf(sc[tid] - smax_s);
      __syncthreads();
      if (tid < 64){
        float ssum = sc[tid] + sc[tid+64];
        #pragma unroll
        for (int o = 32; o; o >>= 1) ssum += __shfl_xor(ssum, o, 64);
        if (tid == 0) ssum_s = ssum;
      }
      __syncthreads();
      const float inv = 1.0f/ssum_s;
      float a0=0.f, a1=0.f, b0=0.f, b1=0.f;   // 2 independent chains x 2 d
      if (ehb){
        const bf16_t* eb = ehb + (size_t)b*Sx*H2 + d0;
        #pragma unroll 8
        for (int s = 0; s < Sx; s += 2){
          const float w0 = sc[s], w1 = sc[s+1];
          bf16x2 v0 = *(const bf16x2*)(eb + (size_t)s*H2);
          bf16x2 v1 = *(const bf16x2*)(eb + (size_t)(s+1)*H2);
          a0 += w0*(float)v0[0]; a1 += w0*(float)v0[1];
          b0 += w1*(float)v1[0]; b1 += w1*(float)v1[1];
        }
      } else {
        const float* eb = eh + (size_t)b*Sx*H2 + d0;
        #pragma unroll 8
        for (int s = 0; s < Sx; s += 2){
          const float w0 = sc[s], w1 = sc[s+1];
          f32x2 v0 = *(const f32x2*)(eb + (size_t)s*H2);
          f32x2 v1 = *(const f32x2*)(eb + (size_t)(s+1)*H2);
          a0 += w0*v0[0]; a1 += w0*v0[1];
          b0 += w1*v1[0]; b1 += w1*v1[1];
        }
      }
      const float c0 = (a0 + b0)*inv, c1 = (a1 + b1)*inv;
      bf16_t cb[2]; cb[0] = (bf16_t)c0; cb[1] = (bf16_t)c1;
      *(uint1*)(xbuf + b*KX + Ex + d0) = *(uint1*)cb;
      if (half == 0) xbuf[b*KX + tid] = (bf16_t)trg[(b*Tx + t)*Ex + tid];
    }
    gsync(barv, ++gen, tid, blk);

    // ================= Phase C: gi GEMM + GRU combine; preout-ctx partial ============
    if (gw < 256){
      const int mt = gw >> 5, ntp = gw & 31;
      const bf16_t* A  = xbuf + (mt*16 + c16)*KX + quad*8;
      const bf16_t* B0 = Wihb + (ntp*16 + c16)*KX + quad*8;
      const bf16_t* B1 = B0 + Hx*KX;
      const bf16_t* B2 = B0 + H2*KX;
      f32x4 ar = {0.f,0.f,0.f,0.f}, az = ar, an = ar;
      for (int k = 0; k < KX; k += 32){
        bf16x8 a = *(const bf16x8*)(A + k);
        ar = __builtin_amdgcn_mfma_f32_16x16x32_bf16(a, *(const bf16x8*)(B0+k), ar, 0,0,0);
        az = __builtin_amdgcn_mfma_f32_16x16x32_bf16(a, *(const bf16x8*)(B1+k), az, 0,0,0);
        an = __builtin_amdgcn_mfma_f32_16x16x32_bf16(a, *(const bf16x8*)(B2+k), an, 0,0,0);
      }
      const int j = ntp*16 + c16;
      const float bir = bih[j], biz = bih[Hx+j], bin = bih[H2+j];
      const float bhr = bhh[j], bhz = bhh[Hx+j], bhn = bhh[H2+j];
      #pragma unroll
      for (int r = 0; r < 4; r++){
        const int b_ = mt*16 + quad*4 + r;
        const float hr = ghf[b_*G3 + j]       + bhr;
        const float hz = ghf[b_*G3 + Hx + j]  + bhz;
        const float hn = ghf[b_*G3 + H2 + j]  + bhn;
        const float rg = fast_sigmoid(ar[r] + bir + hr);
        const float zg = fast_sigmoid(az[r] + biz + hz);
        const float ng = fast_tanh(an[r] + bin + rg*hn);
        const float hold = hf[b_*Hx + j];
        const float hnew = (1.0f - zg)*ng + zg*hold;
        hf[b_*Hx + j] = hnew;
        hb[b_*Hx + j] = (bf16_t)hnew;
        states[(b_*Tx + t)*Hx + j] = hnew;
      }
    } else if (gw < 512){
      // pre_ctx = ctx @ Wp[:,768:1792]^T  -> pre (ctx partial, fp32)
      const int idx = gw - 256;
      const int mt2 = idx >> 5, nt2 = idx & 31;
      const bf16_t* A = xbuf + (mt2*16 + c16)*KX + Ex + quad*8;
      const bf16_t* B = Wpb + (nt2*16 + c16)*KP + (Ex + Hx) + quad*8;
      f32x4 acc = {0.f,0.f,0.f,0.f};
      for (int k = 0; k < H2; k += 32)
        acc = __builtin_amdgcn_mfma_f32_16x16x32_bf16(*(const bf16x8*)(A+k),
                                                      *(const bf16x8*)(B+k), acc, 0,0,0);
      #pragma unroll
      for (int r = 0; r < 4; r++){
        const int b_ = mt2*16 + quad*4 + r;
        pre[(b_*Tx + t)*Hx + nt2*16 + c16] = acc[r];
      }
    }
    gsync(barv, ++gen, tid, blk);
  }
}

// ------- preout += [trg | states] @ Wp[:,0:768]^T  (adds onto ctx partial in pre) -----
__global__ void preout_gemm(const bf16_t* __restrict__ trgb, const float* __restrict__ states,
                            const bf16_t* __restrict__ Wpb, float* __restrict__ pre){
  const int gwid = (blockIdx.x*blockDim.x + threadIdx.x) >> 6;  // 0..32767
  const int lane = threadIdx.x & 63;
  const int quad = lane >> 4, c16 = lane & 15;
  const int mt = gwid >> 5, nt = gwid & 31;
  const int m = mt*16 + c16;
  const bf16_t* Bp = Wpb + (nt*16 + c16)*KP + quad*8;
  f32x4 acc = {0.f,0.f,0.f,0.f};
  const bf16_t* Ae = trgb + m*Ex + quad*8;
  for (int k = 0; k < Ex; k += 32)
    acc = __builtin_amdgcn_mfma_f32_16x16x32_bf16(*(const bf16x8*)(Ae+k),
                                                  *(const bf16x8*)(Bp+k), acc, 0,0,0);
  const float* As = states + m*Hx + quad*8;
  for (int k = 0; k < Hx; k += 32)
    acc = __builtin_amdgcn_mfma_f32_16x16x32_bf16(ld_cvt8(As+k),
                                                  *(const bf16x8*)(Bp+Ex+k), acc, 0,0,0);
  float* C = pre + mt*16*Hx + nt*16;
  #pragma unroll
  for (int r = 0; r < 4; r++){
    const int o = (quad*4 + r)*Hx + c16;
    C[o] = acc[r] + C[o];
  }
}

// ---------------- hidden (hT) + cell_state (zeros) ------------------------------------
__global__ void finalize_kernel(const float* __restrict__ hf,
                                float* __restrict__ hid, float* __restrict__ cell){
  const int i = blockIdx.x*256 + threadIdx.x;  // 0..65535
  hid[i]  = hf[i];
  cell[i] = 0.0f;
}

extern "C" void kernel_launch(void* const* d_in, const int* in_sizes, int n_in,
                              void* d_out, int out_size, void* d_ws, size_t ws_size,
                              hipStream_t stream){
  // --- input remap: find W_ih by its unique size (1536*1280); masks may be absent ---
  int shift = 0;
  for (int i = 0; i < n_in; i++){
    if (in_sizes[i] == 1966080){ shift = i - 8; break; }
  }
  #define IN(k) (((k) < 3) ? d_in[(k)] : d_in[(k) + shift])
  const float* trg = (const float*)IN(0);
  const float* eh  = (const float*)IN(1);
  const float* ef  = (const float*)IN(2);
  const float* Wk  = (const float*)IN(5);
  const float* Wq  = (const float*)IN(6);
  const float* ven = (const float*)IN(7);
  const float* Wih = (const float*)IN(8);
  const float* Whh = (const float*)IN(9);
  const float* bih = (const float*)IN(10);
  const float* bhh = (const float*)IN(11);
  const float* Wb  = (const float*)IN(12);
  const float* bb  = (const float*)IN(13);
  const float* Wp  = (const float*)IN(14);
  #undef IN

  // --- ws layout (bytes) ---
  char* ws = (char*)d_ws;
  bf16_t* xbuf = (bf16_t*)(ws + 0);          //   327,680
  float*  hf   = (float* )(ws + 327680);     //   262,144
  bf16_t* hb   = (bf16_t*)(ws + 589824);     //   131,072
  float*  qf   = (float* )(ws + 720896);     //   262,144
  float*  ghf  = (float* )(ws + 983040);     //   786,432
  bf16_t* Wkb  = (bf16_t*)(ws + 1769472);    // 1,048,576 (free after pk_gemm)
  bf16_t* Wqb  = (bf16_t*)(ws + 2818048);    //   524,288
  bf16_t* Whhb = (bf16_t*)(ws + 3342336);    // 1,572,864
  bf16_t* Wihb = (bf16_t*)(ws + 4915200);    // 3,932,160
  bf16_t* Wpb  = (bf16_t*)(ws + 8847360);    // 1,835,008
  bf16_t* trgb = (bf16_t*)(ws + 10682368);   // 8,388,608
  bf16_t* pk   = (bf16_t*)(ws + 19070976);   // 16,777,216  -> total 35,848,192

  // optional bf16 copy of encoder_hidden (32 MB) if workspace allows
  const size_t EHB_OFF = 35848192;
  const size_t EHB_SZ  = (size_t)Bx*Sx*H2*sizeof(bf16_t);   // 33,554,432
  bf16_t* ehb = (ws_size >= EHB_OFF + EHB_SZ) ? (bf16_t*)(ws + EHB_OFF) : (bf16_t*)0;

  // barrier scratch reuses the Wkb region (dead after pk_gemm)
  unsigned* barv = (unsigned*)Wkb;

  float* out    = (float*)d_out;
  float* states = out + OUT_STATES;
  float* hid    = out + OUT_HID;
  float* pre    = out + OUT_PRE;
  float* cell   = out + OUT_CELL;

  // one-shot converts (fp32 -> bf16)
  cvt_kernel<<<dim3(512),  dim3(256), 0, stream>>>(Wk,  Wkb,  524288);
  cvt_kernel<<<dim3(256),  dim3(256), 0, stream>>>(Wq,  Wqb,  262144);
  cvt_kernel<<<dim3(768),  dim3(256), 0, stream>>>(Whh, Whhb, 786432);
  cvt_kernel<<<dim3(1920), dim3(256), 0, stream>>>(Wih, Wihb, 1966080);
  cvt_kernel<<<dim3(896),  dim3(256), 0, stream>>>(Wp,  Wpb,  917504);
  cvt_kernel<<<dim3(4096), dim3(256), 0, stream>>>(trg, trgb, 4194304);
  if (ehb)
    cvt_kernel<<<dim3(16384), dim3(256), 0, stream>>>(eh, ehb, 16777216);

  bridge_kernel<<<dim3(Bx), dim3(Hx), 0, stream>>>(ef, Wb, bb, hf, hb);
  pk_gemm<<<dim3(8192), dim3(256), 0, stream>>>(eh, Wkb, pk);
  init_bar<<<dim3(3), dim3(256), 0, stream>>>(barv);   // after pk_gemm (reuses Wkb)

  loop_kernel<<<dim3(NBLK), dim3(256), 0, stream>>>(trg, eh, ehb, ven, pk,
                                                    Wqb, Whhb, Wihb, bih, bhh, Wpb,
                                                    xbuf, qf, ghf, hf, hb,
                                                    states, pre, barv);

  preout_gemm<<<dim3(8192), dim3(256), 0, stream>>>(trgb, states, Wpb, pre);
  finalize_kernel<<<dim3(256), dim3(256), 0, stream>>>(hf, hid, cell);
}

// Round 4
// 12630.170 us; speedup vs baseline: 1.2997x; 1.2319x over previous
//
#include <hip/hip_runtime.h>
#include <hip/hip_bf16.h>

typedef __bf16 bf16_t;
typedef __bf16 bf16x8 __attribute__((ext_vector_type(8)));
typedef __bf16 bf16x2 __attribute__((ext_vector_type(2)));
typedef float  f32x4  __attribute__((ext_vector_type(4)));
typedef float  f32x2  __attribute__((ext_vector_type(2)));

#define Bx 128
#define Sx 128
#define Tx 128
#define Ex 256
#define Hx 512
#define H2 1024
#define G3 1536
#define KX 1280   // E + 2H  (GRU input width)
#define KP 1792   // E + H + 2H (preout width)

#define NBLK 256  // persistent grid: 256 blocks x 256 threads (1 block/CU)
#define NGRP 16   // barrier groups (separate cache lines)
#define FLAG_OFF 512  // word offset of replicated generation flags (16 lines)

// ---- output section offsets (elements, fp32) ----
#define OUT_STATES 0
#define OUT_HID    8388608   // B*T*H
#define OUT_PRE    8454144   // + B*H
#define OUT_CELL   16842752  // + B*T*H

__device__ __forceinline__ float fast_tanh(float x){
  float e = __expf(2.0f*x);
  return 1.0f - 2.0f/(e + 1.0f);   // safe at +/-inf
}
__device__ __forceinline__ float fast_sigmoid(float x){
  return 1.0f/(1.0f + __expf(-x));
}

// load 8 contiguous fp32 and round to bf16x8 (RNE via HW cvt)
__device__ __forceinline__ bf16x8 ld_cvt8(const float* p){
  f32x4 a = *(const f32x4*)p;
  f32x4 b = *(const f32x4*)(p+4);
  bf16x8 r;
  r[0]=(bf16_t)a[0]; r[1]=(bf16_t)a[1]; r[2]=(bf16_t)a[2]; r[3]=(bf16_t)a[3];
  r[4]=(bf16_t)b[0]; r[5]=(bf16_t)b[1]; r[6]=(bf16_t)b[2]; r[7]=(bf16_t)b[3];
  return r;
}

// NT GEMM tile (both operands already bf16): C[16,16] += A[16,K] * W[16,K]^T
__device__ __forceinline__ f32x4 gemm_tile_bb(const bf16_t* A, int lda,
                                              const bf16_t* W, int ldw, int K, int lane){
  const int quad = lane >> 4, c = lane & 15;
  const bf16_t* pa = A + c*lda + quad*8;
  const bf16_t* pb = W + c*ldw + quad*8;
  f32x4 acc = {0.f,0.f,0.f,0.f};
  for (int k = 0; k < K; k += 32)
    acc = __builtin_amdgcn_mfma_f32_16x16x32_bf16(*(const bf16x8*)(pa+k),
                                                  *(const bf16x8*)(pb+k), acc, 0, 0, 0);
  return acc;
}

__device__ __forceinline__ void store_tile_f32(float* C, int ldc, f32x4 acc, int lane){
  const int quad = lane >> 4, c = lane & 15;
  #pragma unroll
  for (int r = 0; r < 4; r++) C[(quad*4 + r)*ldc + c] = acc[r];
}

// ---------------- hierarchical grid barrier, replicated release flags -----------------
// barv words: group counter g at barv[g*32] (monotonic); replicated generation flags at
// barv[FLAG_OFF + g*32]. Only ~16 blocks poll each line -> no single-line poll storm.
__device__ __forceinline__ void gsync(unsigned* __restrict__ barv, unsigned next,
                                      int tid, int blk){
  __syncthreads();
  if (tid == 0){
    __builtin_amdgcn_fence(__ATOMIC_RELEASE, "agent");       // publish my writes
    __hip_atomic_fetch_add(&barv[(blk & (NGRP-1))*32], 1u,
                           __ATOMIC_RELAXED, __HIP_MEMORY_SCOPE_AGENT);
  }
  if (blk == 0){
    if (tid < NGRP){
      const unsigned target = next * (NBLK / NGRP);
      while (__hip_atomic_load(&barv[tid*32], __ATOMIC_RELAXED,
                               __HIP_MEMORY_SCOPE_AGENT) < target)
        __builtin_amdgcn_s_sleep(1);
    }
    __syncthreads();                                          // polls done
    if (tid < NGRP)
      __hip_atomic_store(&barv[FLAG_OFF + tid*32], next, __ATOMIC_RELAXED,
                         __HIP_MEMORY_SCOPE_AGENT);
    if (tid == 0)
      __builtin_amdgcn_fence(__ATOMIC_ACQUIRE, "agent");
  } else {
    if (tid == 0){
      while (__hip_atomic_load(&barv[FLAG_OFF + (blk & (NGRP-1))*32],
                               __ATOMIC_RELAXED, __HIP_MEMORY_SCOPE_AGENT) < next)
        __builtin_amdgcn_s_sleep(2);
      __builtin_amdgcn_fence(__ATOMIC_ACQUIRE, "agent");      // invalidate stale caches
    }
  }
  __syncthreads();
}

// zero counters [0,512) and flags [512,1024): 1024 words, 4 blocks x 256
__global__ void init_bar(unsigned* barv){
  const int i = blockIdx.x*256 + threadIdx.x;
  if (i < FLAG_OFF + NGRP*32)
    __hip_atomic_store(&barv[i], 0u, __ATOMIC_RELAXED, __HIP_MEMORY_SCOPE_AGENT);
}

// ---------------- fp32 -> bf16 convert (n % 4 == 0) -----------------------------------
__global__ void cvt_kernel(const float* __restrict__ in, bf16_t* __restrict__ out, int n){
  const int i = (blockIdx.x*256 + threadIdx.x)*4;
  if (i < n){
    f32x4 v = *(const f32x4*)(in + i);
    bf16_t o[4]; o[0]=(bf16_t)v[0]; o[1]=(bf16_t)v[1]; o[2]=(bf16_t)v[2]; o[3]=(bf16_t)v[3];
    *(ulong1*)(out + i) = *(ulong1*)o;
  }
}

// ---------------- bridge: h0 = tanh(encoder_final @ W_bridge^T + b_bridge) -------------
__global__ void bridge_kernel(const float* __restrict__ ef, const float* __restrict__ Wb,
                              const float* __restrict__ bb,
                              float* __restrict__ hf, bf16_t* __restrict__ hb){
  const int b = blockIdx.x;        // 128
  const int h = threadIdx.x;       // 512
  __shared__ float efs[H2];
  for (int k = threadIdx.x; k < H2; k += blockDim.x) efs[k] = ef[b*H2 + k];
  __syncthreads();
  const float* wrow = Wb + h*H2;
  float acc = bb[h];
  for (int k = 0; k < H2; k += 4){
    f32x4 w = *(const f32x4*)(wrow + k);
    acc += efs[k]*w[0] + efs[k+1]*w[1] + efs[k+2]*w[2] + efs[k+3]*w[3];
  }
  float v = fast_tanh(acc);
  hf[b*Hx + h] = v;
  hb[b*Hx + h] = (bf16_t)v;
}

// ---------------- proj_key = encoder_hidden @ W_key^T  (16384x512, K=1024) -------------
__global__ void pk_gemm(const float* __restrict__ eh, const bf16_t* __restrict__ Wkb,
                        bf16_t* __restrict__ pk){
  const int gwid = (blockIdx.x*blockDim.x + threadIdx.x) >> 6;  // 0..32767
  const int lane = threadIdx.x & 63;
  const int quad = lane >> 4, c = lane & 15;
  const int mt = gwid >> 5;   // 1024 m-tiles
  const int nt = gwid & 31;   // 32 n-tiles
  const float*  pa = eh  + (mt*16 + c)*H2 + quad*8;
  const bf16_t* pb = Wkb + (nt*16 + c)*H2 + quad*8;
  f32x4 acc = {0.f,0.f,0.f,0.f};
  for (int k = 0; k < H2; k += 32)
    acc = __builtin_amdgcn_mfma_f32_16x16x32_bf16(ld_cvt8(pa + k),
                                                  *(const bf16x8*)(pb + k), acc, 0,0,0);
  bf16_t* C = pk + mt*16*Hx + nt*16;
  #pragma unroll
  for (int r = 0; r < 4; r++) C[(quad*4 + r)*Hx + c] = (bf16_t)acc[r];
}

// ---------------- persistent loop kernel: 128 steps, 3 grid barriers per step ----------
__global__ void __launch_bounds__(256)
loop_kernel(const float* __restrict__ trg, const float* __restrict__ eh,
            const bf16_t* __restrict__ ehb,            // bf16 copy of eh (may be null)
            const float* __restrict__ ven, const bf16_t* __restrict__ pk,
            const bf16_t* __restrict__ Wqb, const bf16_t* __restrict__ Whhb,
            const bf16_t* __restrict__ Wihb, const float* __restrict__ bih,
            const float* __restrict__ bhh, const bf16_t* __restrict__ Wpb,
            bf16_t* __restrict__ xbuf, float* __restrict__ qf, float* __restrict__ ghf,
            float* __restrict__ hf, bf16_t* __restrict__ hb,
            float* __restrict__ states, float* __restrict__ pre,
            unsigned* __restrict__ barv){
  const int tid  = threadIdx.x;
  const int lane = tid & 63;
  const int wid  = tid >> 6;
  const int blk  = blockIdx.x;          // 0..255
  const int gw   = blk*4 + wid;         // 0..1023
  const int quad = lane >> 4, c16 = lane & 15;

  // phase-B identity (one (b,half) job per block)
  const int b    = blk >> 1;
  const int half = blk & 1;

  __shared__ float sc[Sx];
  __shared__ float red[4][Hx];          // per-wave context partials (8 KB)
  __shared__ float smax_s, ssum_s;

  // v_energy is step-invariant: lane owns h = lane*8 .. lane*8+7
  float vv[8];
  *(f32x4*)(vv)   = *(const f32x4*)(ven + lane*8);
  *(f32x4*)(vv+4) = *(const f32x4*)(ven + lane*8 + 4);

  unsigned gen = 0;

  for (int t = 0; t < Tx; t++){
    // ================= Phase A: q = h@Wq^T, gh = h@Whh^T =================
    if (gw < 256){
      const int mt = gw >> 5, nt = gw & 31;
      f32x4 acc = gemm_tile_bb(hb + mt*16*Hx, Hx, Wqb + nt*16*Hx, Hx, Hx, lane);
      store_tile_f32(qf + mt*16*Hx + nt*16, Hx, acc, lane);
    } else {
      const int idx = gw - 256;              // 0..767
      const int mt = idx/96, nt = idx%96;
      f32x4 acc = gemm_tile_bb(hb + mt*16*Hx, Hx, Whhb + nt*16*Hx, Hx, Hx, lane);
      store_tile_f32(ghf + mt*16*G3 + nt*16, G3, acc, lane);
    }
    gsync(barv, ++gen, tid, blk);

    // ================= Phase B: scores -> softmax -> context =================
    {
      float qv[8];
      *(f32x4*)(qv)   = *(const f32x4*)(qf + b*Hx + lane*8);
      *(f32x4*)(qv+4) = *(const f32x4*)(qf + b*Hx + lane*8 + 4);

      #pragma unroll 4
      for (int j = 0; j < 32; j++){
        const int s = wid*32 + j;
        bf16x8 rw = *(const bf16x8*)(pk + (size_t)(b*Sx + s)*Hx + lane*8);
        float p = 0.f;
        #pragma unroll
        for (int i = 0; i < 8; i++)
          p += fast_tanh(qv[i] + (float)rw[i])*vv[i];
        #pragma unroll
        for (int o = 32; o; o >>= 1) p += __shfl_xor(p, o, 64);
        if (lane == 0) sc[s] = p;
      }
      __syncthreads();
      if (tid < 64){
        float m = fmaxf(sc[tid], sc[tid+64]);
        #pragma unroll
        for (int o = 32; o; o >>= 1) m = fmaxf(m, __shfl_xor(m, o, 64));
        if (tid == 0) smax_s = m;
      }
      __syncthreads();
      if (tid < 128) sc[tid] = __expf(sc[tid] - smax_s);
      __syncthreads();
      const float inv = 1.0f/ssum_s;  // (placeholder read ordering; real read below)
      (void)inv;
      if (tid < 64){
        float ssum = sc[tid] + sc[tid+64];
        #pragma unroll
        for (int o = 32; o; o >>= 1) ssum += __shfl_xor(ssum, o, 64);
        if (tid == 0) ssum_s = ssum;
      }
      __syncthreads();

      // context: wave w owns rows {w, w+4, ...}; lane owns 8 contiguous d (16B loads)
      f32x4 c0 = {0.f,0.f,0.f,0.f}, c1 = {0.f,0.f,0.f,0.f};
      if (ehb){
        const bf16_t* eb = ehb + (size_t)b*Sx*H2 + half*Hx + lane*8;
        #pragma unroll 8
        for (int k = 0; k < 32; k++){
          const int s = (k<<2) + wid;
          const float w = sc[s];
          bf16x8 v = *(const bf16x8*)(eb + (size_t)s*H2);
          c0[0] += w*(float)v[0]; c0[1] += w*(float)v[1];
          c0[2] += w*(float)v[2]; c0[3] += w*(float)v[3];
          c1[0] += w*(float)v[4]; c1[1] += w*(float)v[5];
          c1[2] += w*(float)v[6]; c1[3] += w*(float)v[7];
        }
      } else {
        const float* ef2 = eh + (size_t)b*Sx*H2 + half*Hx + lane*8;
        #pragma unroll 4
        for (int k = 0; k < 32; k++){
          const int s = (k<<2) + wid;
          const float w = sc[s];
          f32x4 va = *(const f32x4*)(ef2 + (size_t)s*H2);
          f32x4 vb = *(const f32x4*)(ef2 + (size_t)s*H2 + 4);
          c0[0] += w*va[0]; c0[1] += w*va[1]; c0[2] += w*va[2]; c0[3] += w*va[3];
          c1[0] += w*vb[0]; c1[1] += w*vb[1]; c1[2] += w*vb[2]; c1[3] += w*vb[3];
        }
      }
      *(f32x4*)(&red[wid][lane*8])     = c0;
      *(f32x4*)(&red[wid][lane*8 + 4]) = c1;
      __syncthreads();
      const float invs = 1.0f/ssum_s;
      const int d = tid*2;
      float r0 = red[0][d]   + red[1][d]   + red[2][d]   + red[3][d];
      float r1 = red[0][d+1] + red[1][d+1] + red[2][d+1] + red[3][d+1];
      r0 *= invs; r1 *= invs;
      bf16_t cbv[2]; cbv[0] = (bf16_t)r0; cbv[1] = (bf16_t)r1;
      *(uint1*)(xbuf + b*KX + Ex + half*Hx + d) = *(uint1*)cbv;
      if (half == 0) xbuf[b*KX + tid] = (bf16_t)trg[(b*Tx + t)*Ex + tid];
    }
    gsync(barv, ++gen, tid, blk);

    // ================= Phase C: gi GEMM + GRU combine; preout-ctx partial ============
    if (gw < 256){
      const int mt = gw >> 5, ntp = gw & 31;
      const bf16_t* A  = xbuf + (mt*16 + c16)*KX + quad*8;
      const bf16_t* B0 = Wihb + (ntp*16 + c16)*KX + quad*8;
      const bf16_t* B1 = B0 + Hx*KX;
      const bf16_t* B2 = B0 + H2*KX;
      f32x4 ar = {0.f,0.f,0.f,0.f}, az = ar, an = ar;
      for (int k = 0; k < KX; k += 32){
        bf16x8 a = *(const bf16x8*)(A + k);
        ar = __builtin_amdgcn_mfma_f32_16x16x32_bf16(a, *(const bf16x8*)(B0+k), ar, 0,0,0);
        az = __builtin_amdgcn_mfma_f32_16x16x32_bf16(a, *(const bf16x8*)(B1+k), az, 0,0,0);
        an = __builtin_amdgcn_mfma_f32_16x16x32_bf16(a, *(const bf16x8*)(B2+k), an, 0,0,0);
      }
      const int j = ntp*16 + c16;
      const float bir = bih[j], biz = bih[Hx+j], bin = bih[H2+j];
      const float bhr = bhh[j], bhz = bhh[Hx+j], bhn = bhh[H2+j];
      #pragma unroll
      for (int r = 0; r < 4; r++){
        const int b_ = mt*16 + quad*4 + r;
        const float hr = ghf[b_*G3 + j]       + bhr;
        const float hz = ghf[b_*G3 + Hx + j]  + bhz;
        const float hn = ghf[b_*G3 + H2 + j]  + bhn;
        const float rg = fast_sigmoid(ar[r] + bir + hr);
        const float zg = fast_sigmoid(az[r] + biz + hz);
        const float ng = fast_tanh(an[r] + bin + rg*hn);
        const float hold = hf[b_*Hx + j];
        const float hnew = (1.0f - zg)*ng + zg*hold;
        hf[b_*Hx + j] = hnew;
        hb[b_*Hx + j] = (bf16_t)hnew;
        states[(b_*Tx + t)*Hx + j] = hnew;
      }
    } else if (gw < 512){
      // pre_ctx = ctx @ Wp[:,768:1792]^T  -> pre (ctx partial, fp32)
      const int idx = gw - 256;
      const int mt2 = idx >> 5, nt2 = idx & 31;
      const bf16_t* A = xbuf + (mt2*16 + c16)*KX + Ex + quad*8;
      const bf16_t* B = Wpb + (nt2*16 + c16)*KP + (Ex + Hx) + quad*8;
      f32x4 acc = {0.f,0.f,0.f,0.f};
      for (int k = 0; k < H2; k += 32)
        acc = __builtin_amdgcn_mfma_f32_16x16x32_bf16(*(const bf16x8*)(A+k),
                                                      *(const bf16x8*)(B+k), acc, 0,0,0);
      #pragma unroll
      for (int r = 0; r < 4; r++){
        const int b_ = mt2*16 + quad*4 + r;
        pre[(b_*Tx + t)*Hx + nt2*16 + c16] = acc[r];
      }
    }
    gsync(barv, ++gen, tid, blk);
  }
}

// ------- preout += [trg | states] @ Wp[:,0:768]^T  (adds onto ctx partial in pre) -----
__global__ void preout_gemm(const bf16_t* __restrict__ trgb, const float* __restrict__ states,
                            const bf16_t* __restrict__ Wpb, float* __restrict__ pre){
  const int gwid = (blockIdx.x*blockDim.x + threadIdx.x) >> 6;  // 0..32767
  const int lane = threadIdx.x & 63;
  const int quad = lane >> 4, c16 = lane & 15;
  const int mt = gwid >> 5, nt = gwid & 31;
  const int m = mt*16 + c16;
  const bf16_t* Bp = Wpb + (nt*16 + c16)*KP + quad*8;
  f32x4 acc = {0.f,0.f,0.f,0.f};
  const bf16_t* Ae = trgb + m*Ex + quad*8;
  for (int k = 0; k < Ex; k += 32)
    acc = __builtin_amdgcn_mfma_f32_16x16x32_bf16(*(const bf16x8*)(Ae+k),
                                                  *(const bf16x8*)(Bp+k), acc, 0,0,0);
  const float* As = states + m*Hx + quad*8;
  for (int k = 0; k < Hx; k += 32)
    acc = __builtin_amdgcn_mfma_f32_16x16x32_bf16(ld_cvt8(As+k),
                                                  *(const bf16x8*)(Bp+Ex+k), acc, 0,0,0);
  float* C = pre + mt*16*Hx + nt*16;
  #pragma unroll
  for (int r = 0; r < 4; r++){
    const int o = (quad*4 + r)*Hx + c16;
    C[o] = acc[r] + C[o];
  }
}

// ---------------- hidden (hT) + cell_state (zeros) ------------------------------------
__global__ void finalize_kernel(const float* __restrict__ hf,
                                float* __restrict__ hid, float* __restrict__ cell){
  const int i = blockIdx.x*256 + threadIdx.x;  // 0..65535
  hid[i]  = hf[i];
  cell[i] = 0.0f;
}

extern "C" void kernel_launch(void* const* d_in, const int* in_sizes, int n_in,
                              void* d_out, int out_size, void* d_ws, size_t ws_size,
                              hipStream_t stream){
  // --- input remap: find W_ih by its unique size (1536*1280); masks may be absent ---
  int shift = 0;
  for (int i = 0; i < n_in; i++){
    if (in_sizes[i] == 1966080){ shift = i - 8; break; }
  }
  #define IN(k) (((k) < 3) ? d_in[(k)] : d_in[(k) + shift])
  const float* trg = (const float*)IN(0);
  const float* eh  = (const float*)IN(1);
  const float* ef  = (const float*)IN(2);
  const float* Wk  = (const float*)IN(5);
  const float* Wq  = (const float*)IN(6);
  const float* ven = (const float*)IN(7);
  const float* Wih = (const float*)IN(8);
  const float* Whh = (const float*)IN(9);
  const float* bih = (const float*)IN(10);
  const float* bhh = (const float*)IN(11);
  const float* Wb  = (const float*)IN(12);
  const float* bb  = (const float*)IN(13);
  const float* Wp  = (const float*)IN(14);
  #undef IN

  // --- ws layout (bytes) ---
  char* ws = (char*)d_ws;
  bf16_t* xbuf = (bf16_t*)(ws + 0);          //   327,680
  float*  hf   = (float* )(ws + 327680);     //   262,144
  bf16_t* hb   = (bf16_t*)(ws + 589824);     //   131,072
  float*  qf   = (float* )(ws + 720896);     //   262,144
  float*  ghf  = (float* )(ws + 983040);     //   786,432
  bf16_t* Wkb  = (bf16_t*)(ws + 1769472);    // 1,048,576 (free after pk_gemm)
  bf16_t* Wqb  = (bf16_t*)(ws + 2818048);    //   524,288
  bf16_t* Whhb = (bf16_t*)(ws + 3342336);    // 1,572,864
  bf16_t* Wihb = (bf16_t*)(ws + 4915200);    // 3,932,160
  bf16_t* Wpb  = (bf16_t*)(ws + 8847360);    // 1,835,008
  bf16_t* trgb = (bf16_t*)(ws + 10682368);   // 8,388,608
  bf16_t* pk   = (bf16_t*)(ws + 19070976);   // 16,777,216  -> total 35,848,192

  // optional bf16 copy of encoder_hidden (32 MB) if workspace allows
  const size_t EHB_OFF = 35848192;
  const size_t EHB_SZ  = (size_t)Bx*Sx*H2*sizeof(bf16_t);   // 33,554,432
  bf16_t* ehb = (ws_size >= EHB_OFF + EHB_SZ) ? (bf16_t*)(ws + EHB_OFF) : (bf16_t*)0;

  // barrier scratch reuses the Wkb region (dead after pk_gemm)
  unsigned* barv = (unsigned*)Wkb;

  float* out    = (float*)d_out;
  float* states = out + OUT_STATES;
  float* hid    = out + OUT_HID;
  float* pre    = out + OUT_PRE;
  float* cell   = out + OUT_CELL;

  // one-shot converts (fp32 -> bf16)
  cvt_kernel<<<dim3(512),  dim3(256), 0, stream>>>(Wk,  Wkb,  524288);
  cvt_kernel<<<dim3(256),  dim3(256), 0, stream>>>(Wq,  Wqb,  262144);
  cvt_kernel<<<dim3(768),  dim3(256), 0, stream>>>(Whh, Whhb, 786432);
  cvt_kernel<<<dim3(1920), dim3(256), 0, stream>>>(Wih, Wihb, 1966080);
  cvt_kernel<<<dim3(896),  dim3(256), 0, stream>>>(Wp,  Wpb,  917504);
  cvt_kernel<<<dim3(4096), dim3(256), 0, stream>>>(trg, trgb, 4194304);
  if (ehb)
    cvt_kernel<<<dim3(16384), dim3(256), 0, stream>>>(eh, ehb, 16777216);

  bridge_kernel<<<dim3(Bx), dim3(Hx), 0, stream>>>(ef, Wb, bb, hf, hb);
  pk_gemm<<<dim3(8192), dim3(256), 0, stream>>>(eh, Wkb, pk);
  init_bar<<<dim3(4), dim3(256), 0, stream>>>(barv);   // after pk_gemm (reuses Wkb)

  loop_kernel<<<dim3(NBLK), dim3(256), 0, stream>>>(trg, eh, ehb, ven, pk,
                                                    Wqb, Whhb, Wihb, bih, bhh, Wpb,
                                                    xbuf, qf, ghf, hf, hb,
                                                    states, pre, barv);

  preout_gemm<<<dim3(8192), dim3(256), 0, stream>>>(trgb, states, Wpb, pre);
  finalize_kernel<<<dim3(256), dim3(256), 0, stream>>>(hf, hid, cell);
}

// Round 5
// 10984.022 us; speedup vs baseline: 1.4944x; 1.1499x over previous
//
#include <hip/hip_runtime.h>
#include <hip/hip_bf16.h>

typedef __bf16 bf16_t;
typedef __bf16 bf16x8 __attribute__((ext_vector_type(8)));
typedef float  f32x4  __attribute__((ext_vector_type(4)));
typedef float  f32x2  __attribute__((ext_vector_type(2)));
typedef unsigned long long u64;

#define Bx 128
#define Sx 128
#define Tx 128
#define Ex 256
#define Hx 512
#define H2 1024
#define G3 1536
#define KX 1280   // E + 2H  (GRU input width)
#define KP 1792   // E + H + 2H (preout width)

#define NBLK 256  // persistent grid: 256 blocks x 256 threads (1 block/CU)
#define NGRP 16   // barrier groups (separate cache lines)
#define FLAG_OFF 512  // word offset of replicated generation flags (16 lines)

// ---- output section offsets (elements, fp32) ----
#define OUT_STATES 0
#define OUT_HID    8388608   // B*T*H
#define OUT_PRE    8454144   // + B*H
#define OUT_CELL   16842752  // + B*T*H

#define ASCOPE __HIP_MEMORY_SCOPE_AGENT

// ---- explicitly-coherent (sc0/sc1) relaxed accesses: performed at L3 coherence point.
// No fences anywhere -> read-only data (pk/ehb/weights) stays L2-resident across steps.
static __device__ __forceinline__ u64 ald8(const void* p){
  return __hip_atomic_load((const u64*)p, __ATOMIC_RELAXED, ASCOPE);
}
static __device__ __forceinline__ void ast4(void* p, unsigned v){
  __hip_atomic_store((unsigned*)p, v, __ATOMIC_RELAXED, ASCOPE);
}
static __device__ __forceinline__ float aldf(const float* p){
  return __hip_atomic_load(p, __ATOMIC_RELAXED, ASCOPE);
}
static __device__ __forceinline__ void astf(float* p, float v){
  __hip_atomic_store(p, v, __ATOMIC_RELAXED, ASCOPE);
}

__device__ __forceinline__ float fast_tanh(float x){
  float e = __expf(2.0f*x);
  return 1.0f - 2.0f/(e + 1.0f);   // safe at +/-inf
}
__device__ __forceinline__ float fast_sigmoid(float x){
  return 1.0f/(1.0f + __expf(-x));
}

// load 8 contiguous fp32 and round to bf16x8 (RNE via HW cvt)
__device__ __forceinline__ bf16x8 ld_cvt8(const float* p){
  f32x4 a = *(const f32x4*)p;
  f32x4 b = *(const f32x4*)(p+4);
  bf16x8 r;
  r[0]=(bf16_t)a[0]; r[1]=(bf16_t)a[1]; r[2]=(bf16_t)a[2]; r[3]=(bf16_t)a[3];
  r[4]=(bf16_t)b[0]; r[5]=(bf16_t)b[1]; r[6]=(bf16_t)b[2]; r[7]=(bf16_t)b[3];
  return r;
}

// ---------------- fence-free hierarchical grid barrier --------------------------------
// Ordering: __syncthreads() drains vmcnt before s_barrier, so all the block's sc1
// stores are at the coherence point before tid0's arrive-RMW. Flag chain is transitive.
__device__ __forceinline__ void gsync(unsigned* __restrict__ barv, unsigned next,
                                      int tid, int blk){
  __syncthreads();
  if (tid == 0)
    __hip_atomic_fetch_add(&barv[(blk & (NGRP-1))*32], 1u,
                           __ATOMIC_RELAXED, ASCOPE);
  if (blk == 0){
    if (tid < NGRP){
      const unsigned target = next * (NBLK / NGRP);
      while (__hip_atomic_load(&barv[tid*32], __ATOMIC_RELAXED, ASCOPE) < target)
        __builtin_amdgcn_s_sleep(1);
    }
    __syncthreads();                                          // polls done
    if (tid < NGRP)
      __hip_atomic_store(&barv[FLAG_OFF + tid*32], next, __ATOMIC_RELAXED, ASCOPE);
  } else if (tid == 0){
    while (__hip_atomic_load(&barv[FLAG_OFF + (blk & (NGRP-1))*32],
                             __ATOMIC_RELAXED, ASCOPE) < next)
      __builtin_amdgcn_s_sleep(2);
  }
  __syncthreads();
}

// zero counters [0,512) and flags [512,1024)
__global__ void init_bar(unsigned* barv){
  const int i = blockIdx.x*256 + threadIdx.x;
  if (i < FLAG_OFF + NGRP*32)
    __hip_atomic_store(&barv[i], 0u, __ATOMIC_RELAXED, ASCOPE);
}

// ---------------- fp32 -> bf16 convert (n % 4 == 0) -----------------------------------
__global__ void cvt_kernel(const float* __restrict__ in, bf16_t* __restrict__ out, int n){
  const int i = (blockIdx.x*256 + threadIdx.x)*4;
  if (i < n){
    f32x4 v = *(const f32x4*)(in + i);
    bf16_t o[4]; o[0]=(bf16_t)v[0]; o[1]=(bf16_t)v[1]; o[2]=(bf16_t)v[2]; o[3]=(bf16_t)v[3];
    *(ulong1*)(out + i) = *(ulong1*)o;
  }
}

// ---------------- bridge: h0 = tanh(encoder_final @ W_bridge^T + b_bridge) -------------
__global__ void bridge_kernel(const float* __restrict__ ef, const float* __restrict__ Wb,
                              const float* __restrict__ bb, float* __restrict__ hf){
  const int b = blockIdx.x;        // 128
  const int h = threadIdx.x;       // 512
  __shared__ float efs[H2];
  for (int k = threadIdx.x; k < H2; k += blockDim.x) efs[k] = ef[b*H2 + k];
  __syncthreads();
  const float* wrow = Wb + h*H2;
  float acc = bb[h];
  for (int k = 0; k < H2; k += 4){
    f32x4 w = *(const f32x4*)(wrow + k);
    acc += efs[k]*w[0] + efs[k+1]*w[1] + efs[k+2]*w[2] + efs[k+3]*w[3];
  }
  hf[b*Hx + h] = fast_tanh(acc);
}

// ---------------- proj_key = encoder_hidden @ W_key^T  (16384x512, K=1024) -------------
__global__ void pk_gemm(const float* __restrict__ eh, const bf16_t* __restrict__ Wkb,
                        bf16_t* __restrict__ pk){
  const int gwid = (blockIdx.x*blockDim.x + threadIdx.x) >> 6;  // 0..32767
  const int lane = threadIdx.x & 63;
  const int quad = lane >> 4, c = lane & 15;
  const int mt = gwid >> 5;   // 1024 m-tiles
  const int nt = gwid & 31;   // 32 n-tiles
  const float*  pa = eh  + (mt*16 + c)*H2 + quad*8;
  const bf16_t* pb = Wkb + (nt*16 + c)*H2 + quad*8;
  f32x4 acc = {0.f,0.f,0.f,0.f};
  for (int k = 0; k < H2; k += 32)
    acc = __builtin_amdgcn_mfma_f32_16x16x32_bf16(ld_cvt8(pa + k),
                                                  *(const bf16x8*)(pb + k), acc, 0,0,0);
  bf16_t* C = pk + mt*16*Hx + nt*16;
  #pragma unroll
  for (int r = 0; r < 4; r++) C[(quad*4 + r)*Hx + c] = (bf16_t)acc[r];
}

// ---------------- persistent loop kernel: 128 steps, 3 grid barriers per step ----------
__global__ void __launch_bounds__(256)
loop_kernel(const float* __restrict__ trg, const float* __restrict__ eh,
            const bf16_t* __restrict__ ehb,            // bf16 copy of eh (may be null)
            const float* __restrict__ ven, const bf16_t* __restrict__ pk,
            const bf16_t* __restrict__ Wqb, const bf16_t* __restrict__ Whhb,
            const bf16_t* __restrict__ Wihb, const float* __restrict__ bih,
            const float* __restrict__ bhh, const bf16_t* __restrict__ Wpb,
            bf16_t* __restrict__ xbuf, float* __restrict__ qf, float* __restrict__ ghf,
            float* __restrict__ hf,
            float* __restrict__ states, float* __restrict__ pre,
            unsigned* __restrict__ barv){
  const int tid  = threadIdx.x;
  const int lane = tid & 63;
  const int wid  = tid >> 6;
  const int blk  = blockIdx.x;          // 0..255
  const int gw   = blk*4 + wid;         // 0..1023
  const int quad = lane >> 4, c16 = lane & 15;

  // phase-B identity (one (b,half) job per block)
  const int b    = blk >> 1;
  const int half = blk & 1;

  __shared__ bf16_t shA[16*1280];       // 40 KB staging tile (XOR-swizzled rows)
  __shared__ float sc[Sx];
  __shared__ float red[4][Hx];          // per-wave context partials (8 KB)
  __shared__ float smax_s, ssum_s;

  // v_energy is step-invariant: lane owns h = lane*8 .. lane*8+7
  float vv[8];
  *(f32x4*)(vv)   = *(const f32x4*)(ven + lane*8);
  *(f32x4*)(vv+4) = *(const f32x4*)(ven + lane*8 + 4);

  const int mtA = (blk < 64) ? (blk >> 3) : ((blk*4 - 256)/96);  // phase-A m-tile
  unsigned gen = 0;

  for (int t = 0; t < Tx; t++){
    // ================= Phase A: q = h@Wq^T, gh = h@Whh^T =================
    {
      // stage h m-tile (f32, coherent) -> LDS bf16, XOR-swizzled
      const int row = tid >> 4, c0 = (tid & 15)*32, swr = (row & 7) << 3;
      const float* src = hf + (mtA*16 + row)*Hx + c0;
      bf16_t* dst = shA + row*512;
      #pragma unroll
      for (int i = 0; i < 4; i++){
        union{ u64 u[4]; float f[8]; } U;
        U.u[0]=ald8(src+i*8);   U.u[1]=ald8(src+i*8+2);
        U.u[2]=ald8(src+i*8+4); U.u[3]=ald8(src+i*8+6);
        bf16x8 v;
        #pragma unroll
        for (int j = 0; j < 8; j++) v[j] = (bf16_t)U.f[j];
        *(bf16x8*)(dst + (((tid & 15)*32 + i*8) ^ swr)) = v;
      }
      (void)c0;
    }
    __syncthreads();
    {
      const int sw = (c16 & 7) << 3;
      const bf16_t* pa = shA + c16*512;
      if (gw < 256){
        const int nt = gw & 31;
        const bf16_t* pb = Wqb + (nt*16 + c16)*Hx + quad*8;
        f32x4 acc = {0.f,0.f,0.f,0.f};
        for (int k = 0; k < Hx; k += 32)
          acc = __builtin_amdgcn_mfma_f32_16x16x32_bf16(
                  *(const bf16x8*)(pa + ((quad*8 + k) ^ sw)),
                  *(const bf16x8*)(pb + k), acc, 0,0,0);
        #pragma unroll
        for (int r = 0; r < 4; r++)
          astf(qf + (mtA*16 + quad*4 + r)*Hx + nt*16 + c16, acc[r]);
      } else {
        const int nt = (gw - 256) % 96;
        const bf16_t* pb = Whhb + (nt*16 + c16)*Hx + quad*8;
        f32x4 acc = {0.f,0.f,0.f,0.f};
        for (int k = 0; k < Hx; k += 32)
          acc = __builtin_amdgcn_mfma_f32_16x16x32_bf16(
                  *(const bf16x8*)(pa + ((quad*8 + k) ^ sw)),
                  *(const bf16x8*)(pb + k), acc, 0,0,0);
        #pragma unroll
        for (int r = 0; r < 4; r++)
          astf(ghf + (mtA*16 + quad*4 + r)*G3 + nt*16 + c16, acc[r]);
      }
    }
    gsync(barv, ++gen, tid, blk);

    // ================= Phase B: scores -> softmax -> context =================
    {
      float qv[8];
      #pragma unroll
      for (int i = 0; i < 4; i++){
        union{ u64 u; float f[2]; } Q;
        Q.u = ald8(qf + b*Hx + lane*8 + i*2);
        qv[i*2] = Q.f[0]; qv[i*2+1] = Q.f[1];
      }

      #pragma unroll 4
      for (int j = 0; j < 32; j++){
        const int s = wid*32 + j;
        bf16x8 rw = *(const bf16x8*)(pk + (size_t)(b*Sx + s)*Hx + lane*8);  // L2-warm
        float p = 0.f;
        #pragma unroll
        for (int i = 0; i < 8; i++)
          p += fast_tanh(qv[i] + (float)rw[i])*vv[i];
        #pragma unroll
        for (int o = 32; o; o >>= 1) p += __shfl_xor(p, o, 64);
        if (lane == 0) sc[s] = p;
      }
      __syncthreads();
      if (tid < 64){
        float m = fmaxf(sc[tid], sc[tid+64]);
        #pragma unroll
        for (int o = 32; o; o >>= 1) m = fmaxf(m, __shfl_xor(m, o, 64));
        if (tid == 0) smax_s = m;
      }
      __syncthreads();
      if (tid < 128) sc[tid] = __expf(sc[tid] - smax_s);
      __syncthreads();
      if (tid < 64){
        float ssum = sc[tid] + sc[tid+64];
        #pragma unroll
        for (int o = 32; o; o >>= 1) ssum += __shfl_xor(ssum, o, 64);
        if (tid == 0) ssum_s = ssum;
      }
      __syncthreads();

      // context: wave w owns rows {w, w+4, ...}; lane owns 8 contiguous d (16B loads)
      f32x4 c0v = {0.f,0.f,0.f,0.f}, c1v = {0.f,0.f,0.f,0.f};
      if (ehb){
        const bf16_t* eb = ehb + (size_t)b*Sx*H2 + half*Hx + lane*8;        // L2-warm
        #pragma unroll 8
        for (int k = 0; k < 32; k++){
          const int s = (k<<2) + wid;
          const float w = sc[s];
          bf16x8 v = *(const bf16x8*)(eb + (size_t)s*H2);
          c0v[0] += w*(float)v[0]; c0v[1] += w*(float)v[1];
          c0v[2] += w*(float)v[2]; c0v[3] += w*(float)v[3];
          c1v[0] += w*(float)v[4]; c1v[1] += w*(float)v[5];
          c1v[2] += w*(float)v[6]; c1v[3] += w*(float)v[7];
        }
      } else {
        const float* ef2 = eh + (size_t)b*Sx*H2 + half*Hx + lane*8;
        #pragma unroll 4
        for (int k = 0; k < 32; k++){
          const int s = (k<<2) + wid;
          const float w = sc[s];
          f32x4 va = *(const f32x4*)(ef2 + (size_t)s*H2);
          f32x4 vb = *(const f32x4*)(ef2 + (size_t)s*H2 + 4);
          c0v[0] += w*va[0]; c0v[1] += w*va[1]; c0v[2] += w*va[2]; c0v[3] += w*va[3];
          c1v[0] += w*vb[0]; c1v[1] += w*vb[1]; c1v[2] += w*vb[2]; c1v[3] += w*vb[3];
        }
      }
      *(f32x4*)(&red[wid][lane*8])     = c0v;
      *(f32x4*)(&red[wid][lane*8 + 4]) = c1v;
      __syncthreads();
      const float invs = 1.0f/ssum_s;
      const int d = tid*2;
      float r0 = red[0][d]   + red[1][d]   + red[2][d]   + red[3][d];
      float r1 = red[0][d+1] + red[1][d+1] + red[2][d+1] + red[3][d+1];
      r0 *= invs; r1 *= invs;
      union{ bf16_t h[2]; unsigned u; } P;
      P.h[0] = (bf16_t)r0; P.h[1] = (bf16_t)r1;
      ast4(xbuf + b*KX + Ex + half*Hx + d, P.u);
      if (half == 0 && tid < 128){
        f32x2 tv = *(const f32x2*)(trg + (size_t)(b*Tx + t)*Ex + tid*2);
        union{ bf16_t h[2]; unsigned u; } E;
        E.h[0] = (bf16_t)tv[0]; E.h[1] = (bf16_t)tv[1];
        ast4(xbuf + b*KX + tid*2, E.u);
      }
    }
    gsync(barv, ++gen, tid, blk);

    // ================= Phase C: gi GEMM + GRU combine; preout-ctx partial ============
    if (blk < 64){
      const int mt = blk >> 3;
      { // stage xbuf m-tile (16 x 1280 bf16, coherent) -> LDS, XOR-swizzled
        const int row = tid >> 4, c0 = (tid & 15)*80, swr = (row & 7) << 3;
        const bf16_t* src = xbuf + (size_t)(mt*16 + row)*KX + c0;
        bf16_t* dst = shA + row*1280;
        #pragma unroll
        for (int i = 0; i < 10; i++){
          union{ u64 u[2]; bf16x8 v; } U;
          U.u[0] = ald8(src + i*8);
          U.u[1] = ald8(src + i*8 + 4);
          *(bf16x8*)(dst + ((c0 + i*8) ^ swr)) = U.v;
        }
      }
      __syncthreads();
      const int ntp = (blk & 7)*4 + wid;
      const int sw = (c16 & 7) << 3;
      const bf16_t* pa = shA + c16*1280;
      const bf16_t* B0 = Wihb + (ntp*16 + c16)*KX + quad*8;
      const bf16_t* B1 = B0 + Hx*KX;
      const bf16_t* B2 = B0 + H2*KX;
      f32x4 ar = {0.f,0.f,0.f,0.f}, az = ar, an = ar;
      for (int k = 0; k < KX; k += 32){
        bf16x8 a = *(const bf16x8*)(pa + ((quad*8 + k) ^ sw));
        ar = __builtin_amdgcn_mfma_f32_16x16x32_bf16(a, *(const bf16x8*)(B0+k), ar, 0,0,0);
        az = __builtin_amdgcn_mfma_f32_16x16x32_bf16(a, *(const bf16x8*)(B1+k), az, 0,0,0);
        an = __builtin_amdgcn_mfma_f32_16x16x32_bf16(a, *(const bf16x8*)(B2+k), an, 0,0,0);
      }
      const int j = ntp*16 + c16;
      const float bir = bih[j], biz = bih[Hx+j], bin = bih[H2+j];
      const float bhr = bhh[j], bhz = bhh[Hx+j], bhn = bhh[H2+j];
      #pragma unroll
      for (int r = 0; r < 4; r++){
        const int b_ = mt*16 + quad*4 + r;
        const float hr = aldf(ghf + b_*G3 + j)       + bhr;
        const float hz = aldf(ghf + b_*G3 + Hx + j)  + bhz;
        const float hn = aldf(ghf + b_*G3 + H2 + j)  + bhn;
        const float rg = fast_sigmoid(ar[r] + bir + hr);
        const float zg = fast_sigmoid(az[r] + biz + hz);
        const float ng = fast_tanh(an[r] + bin + rg*hn);
        const float hold = aldf(hf + b_*Hx + j);
        const float hnew = (1.0f - zg)*ng + zg*hold;
        astf(hf + b_*Hx + j, hnew);
        states[(size_t)(b_*Tx + t)*Hx + j] = hnew;
      }
    } else if (blk < 128){
      const int mt2 = (blk - 64) >> 3;
      { // stage ctx part of xbuf m-tile (16 x 1024 bf16) -> LDS, XOR-swizzled
        const int row = tid >> 4, c0 = (tid & 15)*64, swr = (row & 7) << 3;
        const bf16_t* src = xbuf + (size_t)(mt2*16 + row)*KX + Ex + c0;
        bf16_t* dst = shA + row*1024;
        #pragma unroll
        for (int i = 0; i < 8; i++){
          union{ u64 u[2]; bf16x8 v; } U;
          U.u[0] = ald8(src + i*8);
          U.u[1] = ald8(src + i*8 + 4);
          *(bf16x8*)(dst + ((c0 + i*8) ^ swr)) = U.v;
        }
      }
      __syncthreads();
      const int nt2 = ((blk - 64) & 7)*4 + wid;
      const int sw = (c16 & 7) << 3;
      const bf16_t* pa = shA + c16*1024;
      const bf16_t* B = Wpb + (nt2*16 + c16)*KP + (Ex + Hx) + quad*8;
      f32x4 acc = {0.f,0.f,0.f,0.f};
      for (int k = 0; k < H2; k += 32)
        acc = __builtin_amdgcn_mfma_f32_16x16x32_bf16(
                *(const bf16x8*)(pa + ((quad*8 + k) ^ sw)),
                *(const bf16x8*)(B + k), acc, 0,0,0);
      #pragma unroll
      for (int r = 0; r < 4; r++){
        const int b_ = mt2*16 + quad*4 + r;
        pre[(size_t)(b_*Tx + t)*Hx + nt2*16 + c16] = acc[r];
      }
    }
    gsync(barv, ++gen, tid, blk);
  }
}

// ------- preout += [trg | states] @ Wp[:,0:768]^T  (adds onto ctx partial in pre) -----
__global__ void preout_gemm(const bf16_t* __restrict__ trgb, const float* __restrict__ states,
                            const bf16_t* __restrict__ Wpb, float* __restrict__ pre){
  const int gwid = (blockIdx.x*blockDim.x + threadIdx.x) >> 6;  // 0..32767
  const int lane = threadIdx.x & 63;
  const int quad = lane >> 4, c16 = lane & 15;
  const int mt = gwid >> 5, nt = gwid & 31;
  const int m = mt*16 + c16;
  const bf16_t* Bp = Wpb + (nt*16 + c16)*KP + quad*8;
  f32x4 acc = {0.f,0.f,0.f,0.f};
  const bf16_t* Ae = trgb + m*Ex + quad*8;
  for (int k = 0; k < Ex; k += 32)
    acc = __builtin_amdgcn_mfma_f32_16x16x32_bf16(*(const bf16x8*)(Ae+k),
                                                  *(const bf16x8*)(Bp+k), acc, 0,0,0);
  const float* As = states + m*Hx + quad*8;
  for (int k = 0; k < Hx; k += 32)
    acc = __builtin_amdgcn_mfma_f32_16x16x32_bf16(ld_cvt8(As+k),
                                                  *(const bf16x8*)(Bp+Ex+k), acc, 0,0,0);
  float* C = pre + mt*16*Hx + nt*16;
  #pragma unroll
  for (int r = 0; r < 4; r++){
    const int o = (quad*4 + r)*Hx + c16;
    C[o] = acc[r] + C[o];
  }
}

// ---------------- hidden (hT) + cell_state (zeros) ------------------------------------
__global__ void finalize_kernel(const float* __restrict__ hf,
                                float* __restrict__ hid, float* __restrict__ cell){
  const int i = blockIdx.x*256 + threadIdx.x;  // 0..65535
  hid[i]  = hf[i];
  cell[i] = 0.0f;
}

extern "C" void kernel_launch(void* const* d_in, const int* in_sizes, int n_in,
                              void* d_out, int out_size, void* d_ws, size_t ws_size,
                              hipStream_t stream){
  // --- input remap: find W_ih by its unique size (1536*1280); masks may be absent ---
  int shift = 0;
  for (int i = 0; i < n_in; i++){
    if (in_sizes[i] == 1966080){ shift = i - 8; break; }
  }
  #define IN(k) (((k) < 3) ? d_in[(k)] : d_in[(k) + shift])
  const float* trg = (const float*)IN(0);
  const float* eh  = (const float*)IN(1);
  const float* ef  = (const float*)IN(2);
  const float* Wk  = (const float*)IN(5);
  const float* Wq  = (const float*)IN(6);
  const float* ven = (const float*)IN(7);
  const float* Wih = (const float*)IN(8);
  const float* Whh = (const float*)IN(9);
  const float* bih = (const float*)IN(10);
  const float* bhh = (const float*)IN(11);
  const float* Wb  = (const float*)IN(12);
  const float* bb  = (const float*)IN(13);
  const float* Wp  = (const float*)IN(14);
  #undef IN

  // --- ws layout (bytes) ---
  char* ws = (char*)d_ws;
  bf16_t* xbuf = (bf16_t*)(ws + 0);          //   327,680
  float*  hf   = (float* )(ws + 327680);     //   262,144
  float*  qf   = (float* )(ws + 720896);     //   262,144
  float*  ghf  = (float* )(ws + 983040);     //   786,432
  bf16_t* Wkb  = (bf16_t*)(ws + 1769472);    // 1,048,576 (free after pk_gemm)
  bf16_t* Wqb  = (bf16_t*)(ws + 2818048);    //   524,288
  bf16_t* Whhb = (bf16_t*)(ws + 3342336);    // 1,572,864
  bf16_t* Wihb = (bf16_t*)(ws + 4915200);    // 3,932,160
  bf16_t* Wpb  = (bf16_t*)(ws + 8847360);    // 1,835,008
  bf16_t* trgb = (bf16_t*)(ws + 10682368);   // 8,388,608
  bf16_t* pk   = (bf16_t*)(ws + 19070976);   // 16,777,216  -> total 35,848,192

  // optional bf16 copy of encoder_hidden (32 MB) if workspace allows
  const size_t EHB_OFF = 35848192;
  const size_t EHB_SZ  = (size_t)Bx*Sx*H2*sizeof(bf16_t);   // 33,554,432
  bf16_t* ehb = (ws_size >= EHB_OFF + EHB_SZ) ? (bf16_t*)(ws + EHB_OFF) : (bf16_t*)0;

  // barrier scratch reuses the Wkb region (dead after pk_gemm)
  unsigned* barv = (unsigned*)Wkb;

  float* out    = (float*)d_out;
  float* states = out + OUT_STATES;
  float* hid    = out + OUT_HID;
  float* pre    = out + OUT_PRE;
  float* cell   = out + OUT_CELL;

  // one-shot converts (fp32 -> bf16)
  cvt_kernel<<<dim3(512),  dim3(256), 0, stream>>>(Wk,  Wkb,  524288);
  cvt_kernel<<<dim3(256),  dim3(256), 0, stream>>>(Wq,  Wqb,  262144);
  cvt_kernel<<<dim3(768),  dim3(256), 0, stream>>>(Whh, Whhb, 786432);
  cvt_kernel<<<dim3(1920), dim3(256), 0, stream>>>(Wih, Wihb, 1966080);
  cvt_kernel<<<dim3(896),  dim3(256), 0, stream>>>(Wp,  Wpb,  917504);
  cvt_kernel<<<dim3(4096), dim3(256), 0, stream>>>(trg, trgb, 4194304);
  if (ehb)
    cvt_kernel<<<dim3(16384), dim3(256), 0, stream>>>(eh, ehb, 16777216);

  bridge_kernel<<<dim3(Bx), dim3(Hx), 0, stream>>>(ef, Wb, bb, hf);
  pk_gemm<<<dim3(8192), dim3(256), 0, stream>>>(eh, Wkb, pk);
  init_bar<<<dim3(4), dim3(256), 0, stream>>>(barv);   // after pk_gemm (reuses Wkb)

  loop_kernel<<<dim3(NBLK), dim3(256), 0, stream>>>(trg, eh, ehb, ven, pk,
                                                    Wqb, Whhb, Wihb, bih, bhh, Wpb,
                                                    xbuf, qf, ghf, hf,
                                                    states, pre, barv);

  preout_gemm<<<dim3(8192), dim3(256), 0, stream>>>(trgb, states, Wpb, pre);
  finalize_kernel<<<dim3(256), dim3(256), 0, stream>>>(hf, hid, cell);
}

// Round 6
// 7659.410 us; speedup vs baseline: 2.1431x; 1.4341x over previous
//
#include <hip/hip_runtime.h>
#include <hip/hip_bf16.h>

typedef __bf16 bf16_t;
typedef __bf16 bf16x8 __attribute__((ext_vector_type(8)));
typedef float  f32x4  __attribute__((ext_vector_type(4)));
typedef float  f32x2  __attribute__((ext_vector_type(2)));
typedef unsigned long long u64;

#define Bx 128
#define Sx 128
#define Tx 128
#define Ex 256
#define Hx 512
#define H2 1024
#define G3 1536
#define KX 1280   // E + 2H  (GRU input width)
#define KP 1792   // E + H + 2H (preout width)

#define NBLK 256  // persistent grid: 256 blocks x 512 threads (1 block/CU, 2 waves/SIMD)
#define NGRP 16   // barrier groups (separate cache lines)
#define FLAG_OFF 512  // word offset of replicated generation flags (16 lines)

// ---- output section offsets (elements, fp32) ----
#define OUT_STATES 0
#define OUT_HID    8388608   // B*T*H
#define OUT_PRE    8454144   // + B*H
#define OUT_CELL   16842752  // + B*T*H

#define ASCOPE __HIP_MEMORY_SCOPE_AGENT

// ---- explicitly-coherent relaxed accesses (L3 coherence point) -----------------------
static __device__ __forceinline__ u64 ald8(const void* p){
  return __hip_atomic_load((const u64*)p, __ATOMIC_RELAXED, ASCOPE);
}
static __device__ __forceinline__ void ast4(void* p, unsigned v){
  __hip_atomic_store((unsigned*)p, v, __ATOMIC_RELAXED, ASCOPE);
}
static __device__ __forceinline__ float aldf(const float* p){
  return __hip_atomic_load(p, __ATOMIC_RELAXED, ASCOPE);
}
static __device__ __forceinline__ void astf(float* p, float v){
  __hip_atomic_store(p, v, __ATOMIC_RELAXED, ASCOPE);
}

__device__ __forceinline__ float fast_tanh(float x){
  float e = __expf(2.0f*x);
  return 1.0f - 2.0f/(e + 1.0f);   // safe at +/-inf
}
__device__ __forceinline__ float fast_sigmoid(float x){
  return 1.0f/(1.0f + __expf(-x));
}

// load 8 contiguous fp32 and round to bf16x8 (RNE via HW cvt)
__device__ __forceinline__ bf16x8 ld_cvt8(const float* p){
  f32x4 a = *(const f32x4*)p;
  f32x4 b = *(const f32x4*)(p+4);
  bf16x8 r;
  r[0]=(bf16_t)a[0]; r[1]=(bf16_t)a[1]; r[2]=(bf16_t)a[2]; r[3]=(bf16_t)a[3];
  r[4]=(bf16_t)b[0]; r[5]=(bf16_t)b[1]; r[6]=(bf16_t)b[2]; r[7]=(bf16_t)b[3];
  return r;
}

// ---------------- fence-free hierarchical grid barrier --------------------------------
__device__ __forceinline__ void gsync(unsigned* __restrict__ barv, unsigned next,
                                      int tid, int blk){
  __syncthreads();
  if (tid == 0)
    __hip_atomic_fetch_add(&barv[(blk & (NGRP-1))*32], 1u,
                           __ATOMIC_RELAXED, ASCOPE);
  if (blk == 0){
    if (tid < NGRP){
      const unsigned target = next * (NBLK / NGRP);
      while (__hip_atomic_load(&barv[tid*32], __ATOMIC_RELAXED, ASCOPE) < target)
        __builtin_amdgcn_s_sleep(1);
    }
    __syncthreads();                                          // polls done
    if (tid < NGRP)
      __hip_atomic_store(&barv[FLAG_OFF + tid*32], next, __ATOMIC_RELAXED, ASCOPE);
  } else if (tid == 0){
    while (__hip_atomic_load(&barv[FLAG_OFF + (blk & (NGRP-1))*32],
                             __ATOMIC_RELAXED, ASCOPE) < next)
      __builtin_amdgcn_s_sleep(2);
  }
  __syncthreads();
}

// zero counters [0,512) and flags [512,1024)
__global__ void init_bar(unsigned* barv){
  const int i = blockIdx.x*256 + threadIdx.x;
  if (i < FLAG_OFF + NGRP*32)
    __hip_atomic_store(&barv[i], 0u, __ATOMIC_RELAXED, ASCOPE);
}

// ---------------- fp32 -> bf16 convert (n % 4 == 0) -----------------------------------
__global__ void cvt_kernel(const float* __restrict__ in, bf16_t* __restrict__ out, int n){
  const int i = (blockIdx.x*256 + threadIdx.x)*4;
  if (i < n){
    f32x4 v = *(const f32x4*)(in + i);
    bf16_t o[4]; o[0]=(bf16_t)v[0]; o[1]=(bf16_t)v[1]; o[2]=(bf16_t)v[2]; o[3]=(bf16_t)v[3];
    *(ulong1*)(out + i) = *(ulong1*)o;
  }
}

// ---------------- bridge: h0 = tanh(encoder_final @ W_bridge^T + b_bridge) -------------
__global__ void bridge_kernel(const float* __restrict__ ef, const float* __restrict__ Wb,
                              const float* __restrict__ bb, float* __restrict__ hf){
  const int b = blockIdx.x;        // 128
  const int h = threadIdx.x;       // 512
  __shared__ float efs[H2];
  for (int k = threadIdx.x; k < H2; k += blockDim.x) efs[k] = ef[b*H2 + k];
  __syncthreads();
  const float* wrow = Wb + h*H2;
  float acc = bb[h];
  for (int k = 0; k < H2; k += 4){
    f32x4 w = *(const f32x4*)(wrow + k);
    acc += efs[k]*w[0] + efs[k+1]*w[1] + efs[k+2]*w[2] + efs[k+3]*w[3];
  }
  hf[b*Hx + h] = fast_tanh(acc);
}

// ---------------- proj_key = encoder_hidden @ W_key^T  (16384x512, K=1024) -------------
__global__ void pk_gemm(const float* __restrict__ eh, const bf16_t* __restrict__ Wkb,
                        bf16_t* __restrict__ pk){
  const int gwid = (blockIdx.x*blockDim.x + threadIdx.x) >> 6;  // 0..32767
  const int lane = threadIdx.x & 63;
  const int quad = lane >> 4, c = lane & 15;
  const int mt = gwid >> 5;   // 1024 m-tiles
  const int nt = gwid & 31;   // 32 n-tiles
  const float*  pa = eh  + (mt*16 + c)*H2 + quad*8;
  const bf16_t* pb = Wkb + (nt*16 + c)*H2 + quad*8;
  f32x4 acc = {0.f,0.f,0.f,0.f};
  for (int k = 0; k < H2; k += 32)
    acc = __builtin_amdgcn_mfma_f32_16x16x32_bf16(ld_cvt8(pa + k),
                                                  *(const bf16x8*)(pb + k), acc, 0,0,0);
  bf16_t* C = pk + mt*16*Hx + nt*16;
  #pragma unroll
  for (int r = 0; r < 4; r++) C[(quad*4 + r)*Hx + c] = (bf16_t)acc[r];
}

// ---------------- persistent loop kernel: 128 steps, 3 grid barriers per step ----------
// 512 threads: 8 waves. GEMM tiles are computed by wave PAIRS (w, w+4) splitting K,
// partials combined through LDS -> every serial k-loop halves vs the 256-thread version.
__global__ void __launch_bounds__(512, 2)
loop_kernel(const float* __restrict__ trg, const float* __restrict__ eh,
            const bf16_t* __restrict__ ehb,            // bf16 copy of eh (may be null)
            const float* __restrict__ ven, const bf16_t* __restrict__ pk,
            const bf16_t* __restrict__ Wqb, const bf16_t* __restrict__ Whhb,
            const bf16_t* __restrict__ Wihb, const float* __restrict__ bih,
            const float* __restrict__ bhh, const bf16_t* __restrict__ Wpb,
            bf16_t* __restrict__ xbuf, float* __restrict__ qf, float* __restrict__ ghf,
            float* __restrict__ hf,
            float* __restrict__ states, float* __restrict__ pre,
            unsigned* __restrict__ barv){
  const int tid  = threadIdx.x;
  const int lane = tid & 63;
  const int wid  = tid >> 6;          // 0..7
  const int blk  = blockIdx.x;        // 0..255
  const int quad = lane >> 4, c16 = lane & 15;

  // phase-B identity (one (b,half) job per block)
  const int b    = blk >> 1;
  const int half = blk & 1;

  __shared__ bf16_t shA[16*1280];     // 40 KB staging tile (XOR-swizzled rows)
  __shared__ f32x4  pacc[3][8][64];   // 24 KB K-split partial accumulators
  __shared__ float  red[8][Hx];       // 16 KB context partials
  __shared__ float  sc[Sx];
  __shared__ float  smax_s, ssum_s;

  // v_energy is step-invariant: lane owns h = lane*8 .. lane*8+7
  float vv[8];
  *(f32x4*)(vv)   = *(const f32x4*)(ven + lane*8);
  *(f32x4*)(vv+4) = *(const f32x4*)(ven + lane*8 + 4);

  const int mtA   = (blk < 64) ? (blk >> 3) : ((blk*4 - 256)/96);  // phase-A m-tile
  const int jobA  = blk*4 + (wid & 3);   // 0..1023 (q: <256, gh: >=256)
  const int khalfA= (wid >> 2)*256;      // K-split base for phase A
  unsigned gen = 0;

  for (int t = 0; t < Tx; t++){
    // ================= Phase A: q = h@Wq^T, gh = h@Whh^T (K split over wave pairs) ====
    {
      // stage h m-tile (f32, coherent) -> LDS bf16, XOR-swizzled. 512 threads, 16 rows.
      const int row = tid >> 5, c0 = (tid & 31)*16, swr = (row & 7) << 3;
      const float* src = hf + (mtA*16 + row)*Hx + c0;
      bf16_t* dst = shA + row*512;
      #pragma unroll
      for (int i = 0; i < 2; i++){
        union{ u64 u[4]; float f[8]; } U;
        U.u[0]=ald8(src+i*8);   U.u[1]=ald8(src+i*8+2);
        U.u[2]=ald8(src+i*8+4); U.u[3]=ald8(src+i*8+6);
        bf16x8 v;
        #pragma unroll
        for (int j = 0; j < 8; j++) v[j] = (bf16_t)U.f[j];
        *(bf16x8*)(dst + ((c0 + i*8) ^ swr)) = v;
      }
    }
    __syncthreads();
    {
      const int sw = (c16 & 7) << 3;
      const bf16_t* pa = shA + c16*512;
      const bf16_t* pb = (jobA < 256)
        ? Wqb  + ((jobA & 31)*16 + c16)*Hx + quad*8
        : Whhb + (((jobA - 256) % 96)*16 + c16)*Hx + quad*8;
      f32x4 acc = {0.f,0.f,0.f,0.f};
      for (int k = khalfA; k < khalfA + 256; k += 32)
        acc = __builtin_amdgcn_mfma_f32_16x16x32_bf16(
                *(const bf16x8*)(pa + ((quad*8 + k) ^ sw)),
                *(const bf16x8*)(pb + k), acc, 0,0,0);
      pacc[0][wid][lane] = acc;
    }
    __syncthreads();
    if (wid < 4){
      f32x4 acc = pacc[0][wid][lane] + pacc[0][wid+4][lane];
      if (jobA < 256){
        const int nt = jobA & 31;
        #pragma unroll
        for (int r = 0; r < 4; r++)
          astf(qf + (mtA*16 + quad*4 + r)*Hx + nt*16 + c16, acc[r]);
      } else {
        const int nt = (jobA - 256) % 96;
        #pragma unroll
        for (int r = 0; r < 4; r++)
          astf(ghf + (mtA*16 + quad*4 + r)*G3 + nt*16 + c16, acc[r]);
      }
    }
    gsync(barv, ++gen, tid, blk);

    // ================= Phase B: scores -> softmax -> context =================
    {
      float qv[8];
      #pragma unroll
      for (int i = 0; i < 4; i++){
        union{ u64 u; float f[2]; } Q;
        Q.u = ald8(qf + b*Hx + lane*8 + i*2);
        qv[i*2] = Q.f[0]; qv[i*2+1] = Q.f[1];
      }

      #pragma unroll 4
      for (int j = 0; j < 16; j++){
        const int s = wid*16 + j;
        bf16x8 rw = *(const bf16x8*)(pk + (size_t)(b*Sx + s)*Hx + lane*8);
        float p = 0.f;
        #pragma unroll
        for (int i = 0; i < 8; i++)
          p += fast_tanh(qv[i] + (float)rw[i])*vv[i];
        #pragma unroll
        for (int o = 32; o; o >>= 1) p += __shfl_xor(p, o, 64);
        if (lane == 0) sc[s] = p;
      }
      __syncthreads();
      if (tid < 64){
        float m = fmaxf(sc[tid], sc[tid+64]);
        #pragma unroll
        for (int o = 32; o; o >>= 1) m = fmaxf(m, __shfl_xor(m, o, 64));
        if (tid == 0) smax_s = m;
      }
      __syncthreads();
      if (tid < 128) sc[tid] = __expf(sc[tid] - smax_s);
      __syncthreads();
      if (tid < 64){
        float ssum = sc[tid] + sc[tid+64];
        #pragma unroll
        for (int o = 32; o; o >>= 1) ssum += __shfl_xor(ssum, o, 64);
        if (tid == 0) ssum_s = ssum;
      }
      __syncthreads();

      // context: wave w sums rows {w, w+8, ...} (16 rows); lane owns 8 contiguous d
      f32x4 c0v = {0.f,0.f,0.f,0.f}, c1v = {0.f,0.f,0.f,0.f};
      if (ehb){
        const bf16_t* eb = ehb + (size_t)b*Sx*H2 + half*Hx + lane*8;
        #pragma unroll 8
        for (int k = 0; k < 16; k++){
          const int s = (k<<3) + wid;
          const float w = sc[s];
          bf16x8 v = *(const bf16x8*)(eb + (size_t)s*H2);
          c0v[0] += w*(float)v[0]; c0v[1] += w*(float)v[1];
          c0v[2] += w*(float)v[2]; c0v[3] += w*(float)v[3];
          c1v[0] += w*(float)v[4]; c1v[1] += w*(float)v[5];
          c1v[2] += w*(float)v[6]; c1v[3] += w*(float)v[7];
        }
      } else {
        const float* ef2 = eh + (size_t)b*Sx*H2 + half*Hx + lane*8;
        #pragma unroll 4
        for (int k = 0; k < 16; k++){
          const int s = (k<<3) + wid;
          const float w = sc[s];
          f32x4 va = *(const f32x4*)(ef2 + (size_t)s*H2);
          f32x4 vb = *(const f32x4*)(ef2 + (size_t)s*H2 + 4);
          c0v[0] += w*va[0]; c0v[1] += w*va[1]; c0v[2] += w*va[2]; c0v[3] += w*va[3];
          c1v[0] += w*vb[0]; c1v[1] += w*vb[1]; c1v[2] += w*vb[2]; c1v[3] += w*vb[3];
        }
      }
      *(f32x4*)(&red[wid][lane*8])     = c0v;
      *(f32x4*)(&red[wid][lane*8 + 4]) = c1v;
      __syncthreads();
      if (tid < 256){
        const float invs = 1.0f/ssum_s;
        const int d = tid*2;
        float r0 = 0.f, r1 = 0.f;
        #pragma unroll
        for (int w = 0; w < 8; w++){ r0 += red[w][d]; r1 += red[w][d+1]; }
        r0 *= invs; r1 *= invs;
        union{ bf16_t h[2]; unsigned u; } P;
        P.h[0] = (bf16_t)r0; P.h[1] = (bf16_t)r1;
        ast4(xbuf + b*KX + Ex + half*Hx + d, P.u);
      }
      if (half == 0 && tid < 128){
        f32x2 tv = *(const f32x2*)(trg + (size_t)(b*Tx + t)*Ex + tid*2);
        union{ bf16_t h[2]; unsigned u; } E;
        E.h[0] = (bf16_t)tv[0]; E.h[1] = (bf16_t)tv[1];
        ast4(xbuf + b*KX + tid*2, E.u);
      }
    }
    gsync(barv, ++gen, tid, blk);

    // ================= Phase C: gi GEMM + GRU combine; preout-ctx partial ============
    if (blk < 64){
      const int mt = blk >> 3;
      { // stage xbuf m-tile (16 x 1280 bf16, coherent) -> LDS, XOR-swizzled
        const int row = tid >> 5, c0 = (tid & 31)*40, swr = (row & 7) << 3;
        const bf16_t* src = xbuf + (size_t)(mt*16 + row)*KX + c0;
        bf16_t* dst = shA + row*1280;
        #pragma unroll
        for (int i = 0; i < 5; i++){
          union{ u64 u[2]; bf16x8 v; } U;
          U.u[0] = ald8(src + i*8);
          U.u[1] = ald8(src + i*8 + 4);
          *(bf16x8*)(dst + ((c0 + i*8) ^ swr)) = U.v;
        }
      }
      __syncthreads();
      const int ntp = (blk & 7)*4 + (wid & 3);
      const int kb  = (wid >> 2)*640;
      const int sw = (c16 & 7) << 3;
      const bf16_t* pa = shA + c16*1280;
      const bf16_t* B0 = Wihb + (ntp*16 + c16)*KX + quad*8;
      const bf16_t* B1 = B0 + Hx*KX;
      const bf16_t* B2 = B0 + H2*KX;
      f32x4 ar = {0.f,0.f,0.f,0.f}, az = ar, an = ar;
      for (int k = kb; k < kb + 640; k += 32){
        bf16x8 a = *(const bf16x8*)(pa + ((quad*8 + k) ^ sw));
        ar = __builtin_amdgcn_mfma_f32_16x16x32_bf16(a, *(const bf16x8*)(B0+k), ar, 0,0,0);
        az = __builtin_amdgcn_mfma_f32_16x16x32_bf16(a, *(const bf16x8*)(B1+k), az, 0,0,0);
        an = __builtin_amdgcn_mfma_f32_16x16x32_bf16(a, *(const bf16x8*)(B2+k), an, 0,0,0);
      }
      pacc[0][wid][lane] = ar;
      pacc[1][wid][lane] = az;
      pacc[2][wid][lane] = an;
      __syncthreads();
      if (wid < 4){
        f32x4 arT = pacc[0][wid][lane] + pacc[0][wid+4][lane];
        f32x4 azT = pacc[1][wid][lane] + pacc[1][wid+4][lane];
        f32x4 anT = pacc[2][wid][lane] + pacc[2][wid+4][lane];
        const int j = ntp*16 + c16;
        const float bir = bih[j], biz = bih[Hx+j], bin = bih[H2+j];
        const float bhr = bhh[j], bhz = bhh[Hx+j], bhn = bhh[H2+j];
        #pragma unroll
        for (int r = 0; r < 4; r++){
          const int b_ = mt*16 + quad*4 + r;
          const float hr = aldf(ghf + b_*G3 + j)       + bhr;
          const float hz = aldf(ghf + b_*G3 + Hx + j)  + bhz;
          const float hn = aldf(ghf + b_*G3 + H2 + j)  + bhn;
          const float rg = fast_sigmoid(arT[r] + bir + hr);
          const float zg = fast_sigmoid(azT[r] + biz + hz);
          const float ng = fast_tanh(anT[r] + bin + rg*hn);
          const float hold = aldf(hf + b_*Hx + j);
          const float hnew = (1.0f - zg)*ng + zg*hold;
          astf(hf + b_*Hx + j, hnew);
          states[(size_t)(b_*Tx + t)*Hx + j] = hnew;
        }
      }
    } else if (blk < 128){
      const int mt2 = (blk - 64) >> 3;
      { // stage ctx part of xbuf m-tile (16 x 1024 bf16) -> LDS, XOR-swizzled
        const int row = tid >> 5, c0 = (tid & 31)*32, swr = (row & 7) << 3;
        const bf16_t* src = xbuf + (size_t)(mt2*16 + row)*KX + Ex + c0;
        bf16_t* dst = shA + row*1024;
        #pragma unroll
        for (int i = 0; i < 4; i++){
          union{ u64 u[2]; bf16x8 v; } U;
          U.u[0] = ald8(src + i*8);
          U.u[1] = ald8(src + i*8 + 4);
          *(bf16x8*)(dst + ((c0 + i*8) ^ swr)) = U.v;
        }
      }
      __syncthreads();
      const int nt2 = ((blk - 64) & 7)*4 + (wid & 3);
      const int kb  = (wid >> 2)*512;
      const int sw = (c16 & 7) << 3;
      const bf16_t* pa = shA + c16*1024;
      const bf16_t* B = Wpb + (nt2*16 + c16)*KP + (Ex + Hx) + quad*8;
      f32x4 acc = {0.f,0.f,0.f,0.f};
      for (int k = kb; k < kb + 512; k += 32)
        acc = __builtin_amdgcn_mfma_f32_16x16x32_bf16(
                *(const bf16x8*)(pa + ((quad*8 + k) ^ sw)),
                *(const bf16x8*)(B + k), acc, 0,0,0);
      pacc[0][wid][lane] = acc;
      __syncthreads();
      if (wid < 4){
        f32x4 accT = pacc[0][wid][lane] + pacc[0][wid+4][lane];
        #pragma unroll
        for (int r = 0; r < 4; r++){
          const int b_ = mt2*16 + quad*4 + r;
          pre[(size_t)(b_*Tx + t)*Hx + nt2*16 + c16] = accT[r];
        }
      }
    }
    gsync(barv, ++gen, tid, blk);
  }
}

// ------- preout += [trg | states] @ Wp[:,0:768]^T  (adds onto ctx partial in pre) -----
__global__ void preout_gemm(const bf16_t* __restrict__ trgb, const float* __restrict__ states,
                            const bf16_t* __restrict__ Wpb, float* __restrict__ pre){
  const int gwid = (blockIdx.x*blockDim.x + threadIdx.x) >> 6;  // 0..32767
  const int lane = threadIdx.x & 63;
  const int quad = lane >> 4, c16 = lane & 15;
  const int mt = gwid >> 5, nt = gwid & 31;
  const int m = mt*16 + c16;
  const bf16_t* Bp = Wpb + (nt*16 + c16)*KP + quad*8;
  f32x4 acc = {0.f,0.f,0.f,0.f};
  const bf16_t* Ae = trgb + m*Ex + quad*8;
  for (int k = 0; k < Ex; k += 32)
    acc = __builtin_amdgcn_mfma_f32_16x16x32_bf16(*(const bf16x8*)(Ae+k),
                                                  *(const bf16x8*)(Bp+k), acc, 0,0,0);
  const float* As = states + m*Hx + quad*8;
  for (int k = 0; k < Hx; k += 32)
    acc = __builtin_amdgcn_mfma_f32_16x16x32_bf16(ld_cvt8(As+k),
                                                  *(const bf16x8*)(Bp+Ex+k), acc, 0,0,0);
  float* C = pre + mt*16*Hx + nt*16;
  #pragma unroll
  for (int r = 0; r < 4; r++){
    const int o = (quad*4 + r)*Hx + c16;
    C[o] = acc[r] + C[o];
  }
}

// ---------------- hidden (hT) + cell_state (zeros) ------------------------------------
__global__ void finalize_kernel(const float* __restrict__ hf,
                                float* __restrict__ hid, float* __restrict__ cell){
  const int i = blockIdx.x*256 + threadIdx.x;  // 0..65535
  hid[i]  = hf[i];
  cell[i] = 0.0f;
}

extern "C" void kernel_launch(void* const* d_in, const int* in_sizes, int n_in,
                              void* d_out, int out_size, void* d_ws, size_t ws_size,
                              hipStream_t stream){
  // --- input remap: find W_ih by its unique size (1536*1280); masks may be absent ---
  int shift = 0;
  for (int i = 0; i < n_in; i++){
    if (in_sizes[i] == 1966080){ shift = i - 8; break; }
  }
  #define IN(k) (((k) < 3) ? d_in[(k)] : d_in[(k) + shift])
  const float* trg = (const float*)IN(0);
  const float* eh  = (const float*)IN(1);
  const float* ef  = (const float*)IN(2);
  const float* Wk  = (const float*)IN(5);
  const float* Wq  = (const float*)IN(6);
  const float* ven = (const float*)IN(7);
  const float* Wih = (const float*)IN(8);
  const float* Whh = (const float*)IN(9);
  const float* bih = (const float*)IN(10);
  const float* bhh = (const float*)IN(11);
  const float* Wb  = (const float*)IN(12);
  const float* bb  = (const float*)IN(13);
  const float* Wp  = (const float*)IN(14);
  #undef IN

  // --- ws layout (bytes) ---
  char* ws = (char*)d_ws;
  bf16_t* xbuf = (bf16_t*)(ws + 0);          //   327,680
  float*  hf   = (float* )(ws + 327680);     //   262,144
  float*  qf   = (float* )(ws + 720896);     //   262,144
  float*  ghf  = (float* )(ws + 983040);     //   786,432
  bf16_t* Wkb  = (bf16_t*)(ws + 1769472);    // 1,048,576 (free after pk_gemm)
  bf16_t* Wqb  = (bf16_t*)(ws + 2818048);    //   524,288
  bf16_t* Whhb = (bf16_t*)(ws + 3342336);    // 1,572,864
  bf16_t* Wihb = (bf16_t*)(ws + 4915200);    // 3,932,160
  bf16_t* Wpb  = (bf16_t*)(ws + 8847360);    // 1,835,008
  bf16_t* trgb = (bf16_t*)(ws + 10682368);   // 8,388,608
  bf16_t* pk   = (bf16_t*)(ws + 19070976);   // 16,777,216  -> total 35,848,192

  // optional bf16 copy of encoder_hidden (32 MB) if workspace allows
  const size_t EHB_OFF = 35848192;
  const size_t EHB_SZ  = (size_t)Bx*Sx*H2*sizeof(bf16_t);   // 33,554,432
  bf16_t* ehb = (ws_size >= EHB_OFF + EHB_SZ) ? (bf16_t*)(ws + EHB_OFF) : (bf16_t*)0;

  // barrier scratch reuses the Wkb region (dead after pk_gemm)
  unsigned* barv = (unsigned*)Wkb;

  float* out    = (float*)d_out;
  float* states = out + OUT_STATES;
  float* hid    = out + OUT_HID;
  float* pre    = out + OUT_PRE;
  float* cell   = out + OUT_CELL;

  // one-shot converts (fp32 -> bf16)
  cvt_kernel<<<dim3(512),  dim3(256), 0, stream>>>(Wk,  Wkb,  524288);
  cvt_kernel<<<dim3(256),  dim3(256), 0, stream>>>(Wq,  Wqb,  262144);
  cvt_kernel<<<dim3(768),  dim3(256), 0, stream>>>(Whh, Whhb, 786432);
  cvt_kernel<<<dim3(1920), dim3(256), 0, stream>>>(Wih, Wihb, 1966080);
  cvt_kernel<<<dim3(896),  dim3(256), 0, stream>>>(Wp,  Wpb,  917504);
  cvt_kernel<<<dim3(4096), dim3(256), 0, stream>>>(trg, trgb, 4194304);
  if (ehb)
    cvt_kernel<<<dim3(16384), dim3(256), 0, stream>>>(eh, ehb, 16777216);

  bridge_kernel<<<dim3(Bx), dim3(Hx), 0, stream>>>(ef, Wb, bb, hf);
  pk_gemm<<<dim3(8192), dim3(256), 0, stream>>>(eh, Wkb, pk);
  init_bar<<<dim3(4), dim3(256), 0, stream>>>(barv);   // after pk_gemm (reuses Wkb)

  loop_kernel<<<dim3(NBLK), dim3(512), 0, stream>>>(trg, eh, ehb, ven, pk,
                                                    Wqb, Whhb, Wihb, bih, bhh, Wpb,
                                                    xbuf, qf, ghf, hf,
                                                    states, pre, barv);

  preout_gemm<<<dim3(8192), dim3(256), 0, stream>>>(trgb, states, Wpb, pre);
  finalize_kernel<<<dim3(256), dim3(256), 0, stream>>>(hf, hid, cell);
}